// Round 1
// baseline (70783.881 us; speedup 1.0000x reference)
//
#include <hip/hip_runtime.h>
#include <hip/hip_bf16.h>
#include <stdint.h>

#define B_   256
#define S_   256
#define DM   512
#define G4   2048
#define LAT  128
#define PR   128

__device__ __forceinline__ float bf_lo(unsigned u){ return __uint_as_float(u << 16); }
__device__ __forceinline__ float bf_hi(unsigned u){ return __uint_as_float(u & 0xffff0000u); }
__device__ __forceinline__ unsigned short f2bf(float x){
  __hip_bfloat16 h = __float2bfloat16(x);
  unsigned short u; __builtin_memcpy(&u, &h, 2); return u;
}
__device__ __forceinline__ float sigf(float x){ return 1.f/(1.f+__expf(-x)); }
__device__ __forceinline__ float tanhft(float x){ return 1.f - 2.f/(__expf(2.f*x)+1.f); }

// ---------- prep 1: W_comb[2048][16] = W_ih[:, :512] · Wcat, plus folded x-bias ----------
__global__ void k_fold(const float* __restrict__ W_ih,
                       const float* __restrict__ W_cmd, const float* __restrict__ b_cmd,
                       const float* __restrict__ W_coord, const float* __restrict__ b_coord,
                       const float* __restrict__ W_head, const float* __restrict__ b_head,
                       float* __restrict__ W_comb, float* __restrict__ b_fold)
{
  const int g = blockIdx.x;      // 2048 blocks
  const int lane = threadIdx.x;  // 64 threads
  float p[17];
  #pragma unroll
  for (int k=0;k<17;++k) p[k]=0.f;
  for (int d = lane; d < DM; d += 64){
    float w = W_ih[g*640 + d];
    #pragma unroll
    for (int c=0;c<6;++c)  p[c]    += w * W_cmd[d*6+c];
    #pragma unroll
    for (int c=0;c<8;++c)  p[6+c]  += w * W_coord[d*8+c];
    p[14] += w * W_head[d*2+0];
    p[15] += w * W_head[d*2+1];
    p[16] += w * (b_cmd[d] + b_coord[d] + b_head[d]);
  }
  #pragma unroll
  for (int k=0;k<17;++k){
    #pragma unroll
    for (int off=32; off>0; off>>=1) p[k] += __shfl_xor(p[k], off);
  }
  if (lane == 0){
    #pragma unroll
    for (int k=0;k<16;++k) W_comb[g*16+k] = p[k];
    b_fold[g] = p[16];
  }
}

// ---------- prep 2: ctx_proj[b][g] = context[b]·W_ih[g,512:] + b_ih + b_hh + b_fold ----------
__global__ void k_ctx(const float* __restrict__ context, const float* __restrict__ W_ih,
                      const float* __restrict__ b_ih, const float* __restrict__ b_hh,
                      const float* __restrict__ b_fold, float* __restrict__ ctx_proj)
{
  const int idx = blockIdx.x*256 + threadIdx.x;   // 2048 blocks * 256 = B_*G4
  const int b = idx >> 11;
  const int g = idx & 2047;
  float a = b_ih[g] + b_hh[g] + b_fold[g];
  const float4* cp = reinterpret_cast<const float4*>(context + b*LAT);
  const float4* wp = reinterpret_cast<const float4*>(W_ih + g*640 + DM);
  #pragma unroll 8
  for (int l=0; l<LAT/4; ++l){
    float4 c = cp[l], w = wp[l];
    a += c.x*w.x + c.y*w.y + c.z*w.z + c.w*w.w;
  }
  ctx_proj[idx] = a;
}

// ---------- prep 3: bf16 copies of W_hh, W_hr ----------
__global__ void k_cast(const float* __restrict__ Whh, const float* __restrict__ Whr,
                       __hip_bfloat16* __restrict__ Whh_b, __hip_bfloat16* __restrict__ Whr_b)
{
  const int i = blockIdx.x*256 + threadIdx.x;     // 1024 blocks
  if (i < G4*PR)  Whh_b[i] = __float2bfloat16(Whh[i]);
  if (i < PR*DM)  Whr_b[i] = __float2bfloat16(Whr[i]);
}

// ---------- fused LSTM scan + LayerNorm + heads; one block per batch element ----------
__global__ __launch_bounds__(256, 1)
void k_scan(const float* __restrict__ x_std,
            const float* __restrict__ ctx_proj,
            const __hip_bfloat16* __restrict__ Whh_b,
            const __hip_bfloat16* __restrict__ Whr_b,
            const float* __restrict__ W_comb,
            const float* __restrict__ ln_g, const float* __restrict__ ln_b,
            const float* __restrict__ W_out_cmd, const float* __restrict__ b_out_cmd,
            const float* __restrict__ W_out_coord, const float* __restrict__ b_out_coord,
            float* __restrict__ out_cmd, float* __restrict__ out_coord)
{
  const int b  = blockIdx.x;
  const int t  = threadIdx.x;    // 256 threads; thread owns cell dims d0, d0+1
  const int d0 = 2*t;
  const int p  = t & 127;        // W_hr output row
  const int dh = t >> 7;         // which 256-half of h_full this thread reduces

  __shared__ __align__(16) float s_h[128];
  __shared__ __align__(16) float s_hfull[512];
  __shared__ __align__(16) float s_xs[16];
  __shared__ float s_red[128];
  __shared__ float s_r2[4];
  __shared__ float s_hd[64];

  int rows[8];
  #pragma unroll
  for (int r=0;r<8;++r) rows[r] = (r>>1)*DM + d0 + (r&1);   // [i0,i1,f0,f1,g0,g1,o0,o1]

  float ctxp[8];
  #pragma unroll
  for (int r=0;r<8;++r) ctxp[r] = ctx_proj[b*G4 + rows[r]];

  // W_comb rows, packed bf16 in registers (8 rows x 16 cols = 64 u32)
  unsigned wcp[8][8];
  #pragma unroll
  for (int r=0;r<8;++r){
    const float* wr = W_comb + rows[r]*16;
    #pragma unroll
    for (int q=0;q<8;++q)
      wcp[r][q] = (unsigned)f2bf(wr[2*q]) | ((unsigned)f2bf(wr[2*q+1]) << 16);
  }

  // streamed W_hh row base pointers (immediate-offset loads inside the loop)
  const uint4* wp[8];
  #pragma unroll
  for (int r=0;r<8;++r) wp[r] = reinterpret_cast<const uint4*>(Whh_b + rows[r]*PR);

  // W_hr slice resident in registers: row p, 256 d's (32 uint4 = 256 bf16)
  uint4 wr4[32];
  {
    const uint4* q = reinterpret_cast<const uint4*>(Whr_b + p*DM + dh*256);
    #pragma unroll
    for (int j=0;j<32;++j) wr4[j] = q[j];
  }

  float wcm[6], wco[8];
  #pragma unroll
  for (int k=0;k<6;++k) wcm[k] = W_out_cmd[k*PR + p];
  #pragma unroll
  for (int k=0;k<8;++k) wco[k] = W_out_coord[k*134 + p];
  const float lng = ln_g[p], lnb = ln_b[p];

  float c0 = 0.f, c1 = 0.f;
  if (t < 128) s_h[t] = 0.f;
  if (t < 16)  s_xs[t] = x_std[(b*S_ + 0)*16 + t];
  __syncthreads();

  const float4* sh4 = reinterpret_cast<const float4*>(s_h);
  const float4* sx4 = reinterpret_cast<const float4*>(s_xs);
  const float4* hf4 = reinterpret_cast<const float4*>(&s_hfull[dh*256]);

  for (int s = 0; s < S_; ++s){
    // -------- gates: ctx + x_std·W_comb + h·W_hh^T (bf16 stream, double-buffered) --------
    uint4 wbA[8], wbB[8];
    #pragma unroll
    for (int r=0;r<8;++r) wbA[r] = wp[r][0];

    float acc[8];
    #pragma unroll
    for (int r=0;r<8;++r) acc[r] = ctxp[r];

    float xv[16];
    #pragma unroll
    for (int q=0;q<4;++q){
      float4 xx = sx4[q];
      xv[4*q+0]=xx.x; xv[4*q+1]=xx.y; xv[4*q+2]=xx.z; xv[4*q+3]=xx.w;
    }
    #pragma unroll
    for (int r=0;r<8;++r){
      float a = acc[r];
      #pragma unroll
      for (int q=0;q<8;++q)
        a += bf_lo(wcp[r][q])*xv[2*q] + bf_hi(wcp[r][q])*xv[2*q+1];
      acc[r] = a;
    }

    #pragma unroll
    for (int j=0;j<16;++j){
      if (j+1 < 16){
        #pragma unroll
        for (int r=0;r<8;++r){
          if ((j&1)==0) wbB[r] = wp[r][j+1]; else wbA[r] = wp[r][j+1];
        }
      }
      float4 h0 = sh4[2*j];
      float4 h1 = sh4[2*j+1];
      #pragma unroll
      for (int r=0;r<8;++r){
        uint4 w = ((j&1)==0) ? wbA[r] : wbB[r];
        acc[r] += bf_lo(w.x)*h0.x + bf_hi(w.x)*h0.y
                + bf_lo(w.y)*h0.z + bf_hi(w.y)*h0.w
                + bf_lo(w.z)*h1.x + bf_hi(w.z)*h1.y
                + bf_lo(w.w)*h1.z + bf_hi(w.w)*h1.w;
      }
    }

    // -------- cell update --------
    float i0=sigf(acc[0]), i1=sigf(acc[1]);
    float f0=sigf(acc[2]), f1=sigf(acc[3]);
    float g0=tanhft(acc[4]), g1=tanhft(acc[5]);
    float o0=sigf(acc[6]), o1=sigf(acc[7]);
    c0 = f0*c0 + i0*g0;
    c1 = f1*c1 + i1*g1;
    s_hfull[d0]   = o0*tanhft(c0);
    s_hfull[d0+1] = o1*tanhft(c1);
    __syncthreads();                                   // B1

    if (s+1 < S_ && t < 16) s_xs[t] = x_std[(b*S_ + s+1)*16 + t];

    // -------- h = h_full · W_hr^T (weights in regs, h_full broadcast from LDS) --------
    float ah = 0.f;
    #pragma unroll
    for (int j=0;j<32;++j){
      float4 ha = hf4[2*j], hb = hf4[2*j+1];
      uint4 w = wr4[j];
      ah += bf_lo(w.x)*ha.x + bf_hi(w.x)*ha.y
          + bf_lo(w.y)*ha.z + bf_hi(w.y)*ha.w
          + bf_lo(w.z)*hb.x + bf_hi(w.z)*hb.y
          + bf_lo(w.w)*hb.z + bf_hi(w.w)*hb.w;
    }
    if (t >= 128) s_red[p] = ah;
    __syncthreads();                                   // B2

    float hfin = 0.f;
    if (t < 128){
      hfin = ah + s_red[p];
      s_h[p] = hfin;                                   // carried state for next step
      float sm = hfin, sq = hfin*hfin;
      #pragma unroll
      for (int off=32; off>0; off>>=1){
        sm += __shfl_xor(sm, off);
        sq += __shfl_xor(sq, off);
      }
      if ((t&63)==0){ s_r2[(t>>6)*2] = sm; s_r2[(t>>6)*2+1] = sq; }
    }
    __syncthreads();                                   // B3

    if (t < 128){
      float mu   = (s_r2[0]+s_r2[2]) * (1.f/128.f);
      float var  = (s_r2[1]+s_r2[3]) * (1.f/128.f) - mu*mu;
      float rstd = rsqrtf(var + 1e-5f);
      float hn   = (hfin - mu)*rstd*lng + lnb;
      float v[14];
      #pragma unroll
      for (int k=0;k<6;++k) v[k]   = hn*wcm[k];
      #pragma unroll
      for (int k=0;k<8;++k) v[6+k] = hn*wco[k];
      #pragma unroll
      for (int k=0;k<14;++k){
        #pragma unroll
        for (int off=32; off>0; off>>=1) v[k] += __shfl_xor(v[k], off);
      }
      if ((t&63)==0){
        int w = t>>6;
        #pragma unroll
        for (int k=0;k<14;++k) s_hd[w*32+k] = v[k];
      }
    }
    __syncthreads();                                   // B4

    if (t < 6)
      out_cmd[(b*S_+s)*6 + t] = s_hd[t] + s_hd[32+t] + b_out_cmd[t];
    if (t < 8){
      float co = s_hd[6+t] + s_hd[38+t] + b_out_coord[t];
      #pragma unroll
      for (int c=0;c<6;++c)
        co += (s_hd[c] + s_hd[32+c] + b_out_cmd[c]) * W_out_coord[t*134 + 128 + c];
      out_coord[(b*S_+s)*8 + t] = co;
    }
    // no trailing barrier needed: every shared buffer re-written next iteration is
    // separated from this iteration's readers by >=1 of B1..B4 (checked per-buffer).
  }
}

extern "C" void kernel_launch(void* const* d_in, const int* in_sizes, int n_in,
                              void* d_out, int out_size, void* d_ws, size_t ws_size,
                              hipStream_t stream)
{
  const float* x_std       = (const float*)d_in[0];
  const float* context     = (const float*)d_in[1];
  const float* W_cmd       = (const float*)d_in[2];
  const float* b_cmd       = (const float*)d_in[3];
  const float* W_coord     = (const float*)d_in[4];
  const float* b_coord     = (const float*)d_in[5];
  const float* W_head      = (const float*)d_in[6];
  const float* b_head      = (const float*)d_in[7];
  const float* W_ih        = (const float*)d_in[8];
  const float* W_hh        = (const float*)d_in[9];
  const float* W_hr        = (const float*)d_in[10];
  const float* b_ih        = (const float*)d_in[11];
  const float* b_hh        = (const float*)d_in[12];
  const float* ln_g        = (const float*)d_in[13];
  const float* ln_b        = (const float*)d_in[14];
  const float* W_out_cmd   = (const float*)d_in[15];
  const float* b_out_cmd   = (const float*)d_in[16];
  const float* W_out_coord = (const float*)d_in[17];
  const float* b_out_coord = (const float*)d_in[18];

  float* out = (float*)d_out;
  char*  ws  = (char*)d_ws;

  float* W_comb           = (float*)(ws);                       // 131072 B
  float* b_fold           = (float*)(ws + 131072);              // 8192 B
  float* ctx_proj         = (float*)(ws + 139264);              // 2 MB
  __hip_bfloat16* Whh_b   = (__hip_bfloat16*)(ws + 2236416);    // 512 KB
  __hip_bfloat16* Whr_b   = (__hip_bfloat16*)(ws + 2760704);    // 128 KB
  // total ws use: 2891776 B (~2.76 MB)

  k_fold<<<dim3(G4), dim3(64), 0, stream>>>(W_ih, W_cmd, b_cmd, W_coord, b_coord,
                                            W_head, b_head, W_comb, b_fold);
  k_ctx<<<dim3((B_*G4)/256), dim3(256), 0, stream>>>(context, W_ih, b_ih, b_hh,
                                                     b_fold, ctx_proj);
  k_cast<<<dim3((G4*PR)/256), dim3(256), 0, stream>>>(W_hh, W_hr, Whh_b, Whr_b);
  k_scan<<<dim3(B_), dim3(256), 0, stream>>>(x_std, ctx_proj, Whh_b, Whr_b, W_comb,
                                             ln_g, ln_b, W_out_cmd, b_out_cmd,
                                             W_out_coord, b_out_coord,
                                             out, out + B_*S_*6);
}

// Round 2
// 40284.525 us; speedup vs baseline: 1.7571x; 1.7571x over previous
//
#include <hip/hip_runtime.h>
#include <hip/hip_bf16.h>
#include <stdint.h>

#define B_   256
#define S_   256
#define DM   512
#define G4   2048
#define LAT  128
#define PR   128

__device__ __forceinline__ float bf_lo(unsigned u){ return __uint_as_float(u << 16); }
__device__ __forceinline__ float bf_hi(unsigned u){ return __uint_as_float(u & 0xffff0000u); }
__device__ __forceinline__ unsigned short f2bf(float x){
  __hip_bfloat16 h = __float2bfloat16(x);
  unsigned short u; __builtin_memcpy(&u, &h, 2); return u;
}
__device__ __forceinline__ unsigned packbf(float a, float b){
  return (unsigned)f2bf(a) | ((unsigned)f2bf(b) << 16);
}
__device__ __forceinline__ float sigf(float x){ return 1.f/(1.f+__expf(-x)); }
__device__ __forceinline__ float tanhft(float x){ return 1.f - 2.f/(__expf(2.f*x)+1.f); }

// ---------- prep 1: W_comb[2048][16] = W_ih[:, :512] · Wcat, plus folded x-bias ----------
__global__ void k_fold(const float* __restrict__ W_ih,
                       const float* __restrict__ W_cmd, const float* __restrict__ b_cmd,
                       const float* __restrict__ W_coord, const float* __restrict__ b_coord,
                       const float* __restrict__ W_head, const float* __restrict__ b_head,
                       float* __restrict__ W_comb, float* __restrict__ b_fold)
{
  const int g = blockIdx.x;      // 2048 blocks
  const int lane = threadIdx.x;  // 64 threads
  float p[17];
  #pragma unroll
  for (int k=0;k<17;++k) p[k]=0.f;
  for (int d = lane; d < DM; d += 64){
    float w = W_ih[g*640 + d];
    #pragma unroll
    for (int c=0;c<6;++c)  p[c]    += w * W_cmd[d*6+c];
    #pragma unroll
    for (int c=0;c<8;++c)  p[6+c]  += w * W_coord[d*8+c];
    p[14] += w * W_head[d*2+0];
    p[15] += w * W_head[d*2+1];
    p[16] += w * (b_cmd[d] + b_coord[d] + b_head[d]);
  }
  #pragma unroll
  for (int k=0;k<17;++k){
    #pragma unroll
    for (int off=32; off>0; off>>=1) p[k] += __shfl_xor(p[k], off);
  }
  if (lane == 0){
    #pragma unroll
    for (int k=0;k<16;++k) W_comb[g*16+k] = p[k];
    b_fold[g] = p[16];
  }
}

// ---------- prep 2: ctx_proj[b][g] = context[b]·W_ih[g,512:] + b_ih + b_hh + b_fold ----------
__global__ void k_ctx(const float* __restrict__ context, const float* __restrict__ W_ih,
                      const float* __restrict__ b_ih, const float* __restrict__ b_hh,
                      const float* __restrict__ b_fold, float* __restrict__ ctx_proj)
{
  const int idx = blockIdx.x*256 + threadIdx.x;   // 2048 blocks * 256 = B_*G4
  const int b = idx >> 11;
  const int g = idx & 2047;
  float a = b_ih[g] + b_hh[g] + b_fold[g];
  const float4* cp = reinterpret_cast<const float4*>(context + b*LAT);
  const float4* wp = reinterpret_cast<const float4*>(W_ih + g*640 + DM);
  #pragma unroll 8
  for (int l=0; l<LAT/4; ++l){
    float4 c = cp[l], w = wp[l];
    a += c.x*w.x + c.y*w.y + c.z*w.z + c.w*w.w;
  }
  ctx_proj[idx] = a;
}

// ---------- prep 3: W_hh transposed+packed: Whh_p[k8][row] = uint4 of bf16 W_hh[row][8k8..8k8+7] ----------
__global__ void k_packT(const float* __restrict__ Whh, uint4* __restrict__ Whh_p)
{
  const int tid = blockIdx.x*256 + threadIdx.x;   // 128 blocks -> 32768 threads
  const int row = tid & 2047;
  const int k8  = tid >> 11;                      // 0..15
  const float* src = Whh + row*PR + k8*8;
  uint4 d;
  d.x = packbf(src[0], src[1]);
  d.y = packbf(src[2], src[3]);
  d.z = packbf(src[4], src[5]);
  d.w = packbf(src[6], src[7]);
  Whh_p[k8*G4 + row] = d;
}

// ---------- prep 4: bf16 copy of W_hr ----------
__global__ void k_castr(const float* __restrict__ Whr, __hip_bfloat16* __restrict__ Whr_b)
{
  const int i = blockIdx.x*256 + threadIdx.x;     // 256 blocks -> 65536
  Whr_b[i] = __float2bfloat16(Whr[i]);
}

// ---------- fused LSTM scan + LayerNorm + heads; one block per batch element ----------
__global__ __launch_bounds__(512, 2)
void k_scan(const float* __restrict__ x_std,
            const float* __restrict__ ctx_proj,
            const uint4* __restrict__ Whh_p,
            const __hip_bfloat16* __restrict__ Whr_b,
            const float* __restrict__ W_comb,
            const float* __restrict__ ln_g, const float* __restrict__ ln_b,
            const float* __restrict__ W_out_cmd, const float* __restrict__ b_out_cmd,
            const float* __restrict__ W_out_coord, const float* __restrict__ b_out_coord,
            float* __restrict__ out_cmd, float* __restrict__ out_coord)
{
  const int b = blockIdx.x;
  const int t = threadIdx.x;   // 512 threads; thread owns cell dim d = t (rows t+512r)
  const int p = t & 127;       // W_hr output row this thread contributes to
  const int q = t >> 7;        // which 128-slice of h_full this thread reduces

  __shared__ __align__(16) float s_h[128];
  __shared__ __align__(16) float s_hfull[512];
  __shared__ __align__(16) float s_xs[16];
  __shared__ float s_red[384];
  __shared__ float s_r2[4];
  __shared__ float s_hd[64];

  // per-thread constants
  float ctxp[4];
  #pragma unroll
  for (int r=0;r<4;++r) ctxp[r] = ctx_proj[b*G4 + r*DM + t];

  unsigned wcp[4][8];                       // W_comb rows, packed bf16
  #pragma unroll
  for (int r=0;r<4;++r){
    const float* wrow = W_comb + (r*DM + t)*16;
    #pragma unroll
    for (int qq=0; qq<8; ++qq) wcp[r][qq] = packbf(wrow[2*qq], wrow[2*qq+1]);
  }

  // W_hr slice: row p, d in [q*128, q*128+128) -> 16 uint4 (64 VGPRs)
  uint4 wr[16];
  {
    const uint4* wq = reinterpret_cast<const uint4*>(Whr_b + p*DM + q*128);
    #pragma unroll
    for (int j=0;j<16;++j) wr[j] = wq[j];
  }

  float wcm[6], wco[8];
  #pragma unroll
  for (int k=0;k<6;++k) wcm[k] = W_out_cmd[k*PR + p];
  #pragma unroll
  for (int k=0;k<8;++k) wco[k] = W_out_coord[k*134 + p];
  const float lng = ln_g[p], lnb = ln_b[p];

  // coalesced W_hh stream base: row r*512+t, step k8 strides 2048 uint4
  const uint4* base0 = Whh_p + (0*DM + t);
  const uint4* base1 = Whh_p + (1*DM + t);
  const uint4* base2 = Whh_p + (2*DM + t);
  const uint4* base3 = Whh_p + (3*DM + t);

  float c_reg = 0.f;
  if (t < 128) s_h[t] = 0.f;
  if (t < 16)  s_xs[t] = x_std[(b*S_ + 0)*16 + t];
  __syncthreads();

  const float4* sh4 = reinterpret_cast<const float4*>(s_h);
  const float4* sx4 = reinterpret_cast<const float4*>(s_xs);
  const float4* hf4 = reinterpret_cast<const float4*>(&s_hfull[q*128]);

  for (int s = 0; s < S_; ++s){
    float acc[4];
    #pragma unroll
    for (int r=0;r<4;++r) acc[r] = ctxp[r];

    // ---- x_std · W_comb (registers) ----
    {
      float xv[16];
      #pragma unroll
      for (int qq=0; qq<4; ++qq){
        float4 xx = sx4[qq];
        xv[4*qq+0]=xx.x; xv[4*qq+1]=xx.y; xv[4*qq+2]=xx.z; xv[4*qq+3]=xx.w;
      }
      #pragma unroll
      for (int r=0;r<4;++r){
        float a = acc[r];
        #pragma unroll
        for (int qq=0; qq<8; ++qq)
          a += bf_lo(wcp[r][qq])*xv[2*qq] + bf_hi(wcp[r][qq])*xv[2*qq+1];
        acc[r] = a;
      }
    }

    // ---- h · W_hh^T : coalesced packed stream, 3-buffer rotating prefetch ----
    {
      uint4 buf[3][4];
      float hb[2][8];
      buf[0][0]=base0[0];      buf[0][1]=base1[0];      buf[0][2]=base2[0];      buf[0][3]=base3[0];
      buf[1][0]=base0[G4];     buf[1][1]=base1[G4];     buf[1][2]=base2[G4];     buf[1][3]=base3[G4];
      {
        float4 h0 = sh4[0], h1 = sh4[1];
        hb[0][0]=h0.x; hb[0][1]=h0.y; hb[0][2]=h0.z; hb[0][3]=h0.w;
        hb[0][4]=h1.x; hb[0][5]=h1.y; hb[0][6]=h1.z; hb[0][7]=h1.w;
      }
      #pragma unroll
      for (int k8=0; k8<16; ++k8){
        if (k8+2 < 16){
          const int slot = (k8+2)%3, off = (k8+2)*G4;
          buf[slot][0]=base0[off]; buf[slot][1]=base1[off];
          buf[slot][2]=base2[off]; buf[slot][3]=base3[off];
        }
        if (k8+1 < 16){
          float4 h0 = sh4[(k8+1)*2], h1 = sh4[(k8+1)*2+1];
          const int nx = (k8+1)&1;
          hb[nx][0]=h0.x; hb[nx][1]=h0.y; hb[nx][2]=h0.z; hb[nx][3]=h0.w;
          hb[nx][4]=h1.x; hb[nx][5]=h1.y; hb[nx][6]=h1.z; hb[nx][7]=h1.w;
        }
        const float* h8 = hb[k8&1];
        const int cs = k8%3;
        #pragma unroll
        for (int r=0;r<4;++r){
          uint4 w = buf[cs][r];
          acc[r] += bf_lo(w.x)*h8[0] + bf_hi(w.x)*h8[1]
                  + bf_lo(w.y)*h8[2] + bf_hi(w.y)*h8[3]
                  + bf_lo(w.z)*h8[4] + bf_hi(w.z)*h8[5]
                  + bf_lo(w.w)*h8[6] + bf_hi(w.w)*h8[7];
        }
      }
    }

    // ---- cell update ----
    {
      float iv = sigf(acc[0]);
      float fv = sigf(acc[1]);
      float gv = tanhft(acc[2]);
      float ov = sigf(acc[3]);
      c_reg = fv*c_reg + iv*gv;
      s_hfull[t] = ov*tanhft(c_reg);
    }
    __syncthreads();                                   // B1

    if (s+1 < S_ && t < 16) s_xs[t] = x_std[(b*S_ + s+1)*16 + t];

    // ---- h = h_full · W_hr^T (weights in regs, h_full broadcast from LDS) ----
    float ah = 0.f;
    #pragma unroll
    for (int j=0;j<16;++j){
      float4 ha = hf4[2*j], hc = hf4[2*j+1];
      uint4 w = wr[j];
      ah += bf_lo(w.x)*ha.x + bf_hi(w.x)*ha.y
          + bf_lo(w.y)*ha.z + bf_hi(w.y)*ha.w
          + bf_lo(w.z)*hc.x + bf_hi(w.z)*hc.y
          + bf_lo(w.w)*hc.z + bf_hi(w.w)*hc.w;
    }
    if (q) s_red[(q-1)*128 + p] = ah;
    __syncthreads();                                   // B2

    float hfin = 0.f;
    if (t < 128){
      hfin = ah + s_red[p] + s_red[128+p] + s_red[256+p];
      s_h[p] = hfin;                                   // carried state for next step
      float sm = hfin, sq = hfin*hfin;
      #pragma unroll
      for (int off=32; off>0; off>>=1){
        sm += __shfl_xor(sm, off);
        sq += __shfl_xor(sq, off);
      }
      if ((t&63)==0){ s_r2[(t>>6)*2] = sm; s_r2[(t>>6)*2+1] = sq; }
    }
    __syncthreads();                                   // B3

    if (t < 128){
      float mu   = (s_r2[0]+s_r2[2]) * (1.f/128.f);
      float var  = (s_r2[1]+s_r2[3]) * (1.f/128.f) - mu*mu;
      float rstd = rsqrtf(var + 1e-5f);
      float hn   = (hfin - mu)*rstd*lng + lnb;
      float v[14];
      #pragma unroll
      for (int k=0;k<6;++k) v[k]   = hn*wcm[k];
      #pragma unroll
      for (int k=0;k<8;++k) v[6+k] = hn*wco[k];
      #pragma unroll
      for (int k=0;k<14;++k){
        #pragma unroll
        for (int off=32; off>0; off>>=1) v[k] += __shfl_xor(v[k], off);
      }
      if ((t&63)==0){
        int w = t>>6;
        #pragma unroll
        for (int k=0;k<14;++k) s_hd[w*32+k] = v[k];
      }
    }
    __syncthreads();                                   // B4

    if (t < 6)
      out_cmd[(b*S_+s)*6 + t] = s_hd[t] + s_hd[32+t] + b_out_cmd[t];
    if (t < 8){
      float co = s_hd[6+t] + s_hd[38+t] + b_out_coord[t];
      #pragma unroll
      for (int c=0;c<6;++c)
        co += (s_hd[c] + s_hd[32+c] + b_out_cmd[c]) * W_out_coord[t*134 + 128 + c];
      out_coord[(b*S_+s)*8 + t] = co;
    }
    // shared-buffer hazards across the loop wrap are separated by B1..B4 (checked per-buffer)
  }
}

extern "C" void kernel_launch(void* const* d_in, const int* in_sizes, int n_in,
                              void* d_out, int out_size, void* d_ws, size_t ws_size,
                              hipStream_t stream)
{
  const float* x_std       = (const float*)d_in[0];
  const float* context     = (const float*)d_in[1];
  const float* W_cmd       = (const float*)d_in[2];
  const float* b_cmd       = (const float*)d_in[3];
  const float* W_coord     = (const float*)d_in[4];
  const float* b_coord     = (const float*)d_in[5];
  const float* W_head      = (const float*)d_in[6];
  const float* b_head      = (const float*)d_in[7];
  const float* W_ih        = (const float*)d_in[8];
  const float* W_hh        = (const float*)d_in[9];
  const float* W_hr        = (const float*)d_in[10];
  const float* b_ih        = (const float*)d_in[11];
  const float* b_hh        = (const float*)d_in[12];
  const float* ln_g        = (const float*)d_in[13];
  const float* ln_b        = (const float*)d_in[14];
  const float* W_out_cmd   = (const float*)d_in[15];
  const float* b_out_cmd   = (const float*)d_in[16];
  const float* W_out_coord = (const float*)d_in[17];
  const float* b_out_coord = (const float*)d_in[18];

  float* out = (float*)d_out;
  char*  ws  = (char*)d_ws;

  float* W_comb           = (float*)(ws);                       // 131072 B
  float* b_fold           = (float*)(ws + 131072);              // 8192 B
  float* ctx_proj         = (float*)(ws + 139264);              // 2 MB
  uint4* Whh_p            = (uint4*)(ws + 2236416);             // 512 KB (16-aligned)
  __hip_bfloat16* Whr_b   = (__hip_bfloat16*)(ws + 2760704);    // 128 KB
  // total ws use: 2891776 B (~2.76 MB)

  k_fold<<<dim3(G4), dim3(64), 0, stream>>>(W_ih, W_cmd, b_cmd, W_coord, b_coord,
                                            W_head, b_head, W_comb, b_fold);
  k_ctx<<<dim3((B_*G4)/256), dim3(256), 0, stream>>>(context, W_ih, b_ih, b_hh,
                                                     b_fold, ctx_proj);
  k_packT<<<dim3(128), dim3(256), 0, stream>>>(W_hh, Whh_p);
  k_castr<<<dim3(256), dim3(256), 0, stream>>>(W_hr, Whr_b);
  k_scan<<<dim3(B_), dim3(512), 0, stream>>>(x_std, ctx_proj, Whh_p, Whr_b, W_comb,
                                             ln_g, ln_b, W_out_cmd, b_out_cmd,
                                             W_out_coord, b_out_coord,
                                             out, out + B_*S_*6);
}

// Round 4
// 6236.232 us; speedup vs baseline: 11.3504x; 6.4598x over previous
//
#include <hip/hip_runtime.h>
#include <hip/hip_bf16.h>
#include <stdint.h>

#define B_   256
#define S_   256
#define DM   512
#define G4   2048
#define LAT  128
#define PR   128

typedef __bf16 bf16x8 __attribute__((ext_vector_type(8)));
typedef float  f32x4  __attribute__((ext_vector_type(4)));

__device__ __forceinline__ bf16x8 ldg8(const __hip_bfloat16* p){
  uint4 v = *reinterpret_cast<const uint4*>(p);
  return __builtin_bit_cast(bf16x8, v);
}
__device__ __forceinline__ float sigf(float x){ return 1.f/(1.f+__expf(-x)); }
__device__ __forceinline__ float tanhft(float x){ return 1.f - 2.f/(__expf(2.f*x)+1.f); }

// ================= prep 1: W_comb[2048][16] = W_ih[:, :512] · Wcat, + folded x-bias ===========
__global__ void k_fold(const float* __restrict__ W_ih,
                       const float* __restrict__ W_cmd, const float* __restrict__ b_cmd,
                       const float* __restrict__ W_coord, const float* __restrict__ b_coord,
                       const float* __restrict__ W_head, const float* __restrict__ b_head,
                       float* __restrict__ W_comb, float* __restrict__ b_fold)
{
  const int g = blockIdx.x;      // 2048
  const int lane = threadIdx.x;  // 64
  float p[17];
  #pragma unroll
  for (int k=0;k<17;++k) p[k]=0.f;
  for (int d = lane; d < DM; d += 64){
    float w = W_ih[g*640 + d];
    #pragma unroll
    for (int c=0;c<6;++c)  p[c]    += w * W_cmd[d*6+c];
    #pragma unroll
    for (int c=0;c<8;++c)  p[6+c]  += w * W_coord[d*8+c];
    p[14] += w * W_head[d*2+0];
    p[15] += w * W_head[d*2+1];
    p[16] += w * (b_cmd[d] + b_coord[d] + b_head[d]);
  }
  #pragma unroll
  for (int k=0;k<17;++k){
    #pragma unroll
    for (int off=32; off>0; off>>=1) p[k] += __shfl_xor(p[k], off);
  }
  if (lane == 0){
    #pragma unroll
    for (int k=0;k<16;++k) W_comb[g*16+k] = p[k];
    b_fold[g] = p[16];
  }
}

// ================= prep 2: gate-B in fragment-linear order =================================
// Bp[((n*5+kc)*64 + l)*8 + j] = B[k][g] = Wrow[g][k], g=n*16+(l&15), k=kc*32+((l>>4)&3)*8+j
// Wrow[g][k]: k<128 -> W_hh[g][k]; k<144 -> W_comb[g][k-128]; else 0
__global__ void k_bp(const float* __restrict__ Whh, const float* __restrict__ W_comb,
                     __hip_bfloat16* __restrict__ Bp)
{
  const int flat = blockIdx.x*256 + threadIdx.x;   // 1280 blocks -> 327680
  const int j   = flat & 7;
  const int l   = (flat >> 3) & 63;
  const int idx = flat >> 9;                        // n*5 + kc
  const int n   = idx / 5;
  const int kc  = idx - n*5;
  const int g   = n*16 + (l & 15);
  const int k   = kc*32 + ((l >> 4) & 3)*8 + j;
  float v = (k < 128) ? Whh[g*PR + k] : ((k < 144) ? W_comb[g*16 + (k-128)] : 0.f);
  Bp[flat] = __float2bfloat16(v);
}

// ================= prep 3: hr/head-B in fragment-linear order ==============================
// Wr2[((tn*16+kc)*64 + l)*8 + j]: row = tn*16+(l&15), d = kc*32+((l>>4)&3)*8+j
// row<128: W_hr[row][d]; row<142: WheadD[row-128][d] = sum_p ln_g[p]*Wout[row-128][p]*W_hr[p][d]; else 0
__global__ void k_wr2(const float* __restrict__ Whr, const float* __restrict__ ln_g,
                      const float* __restrict__ Wocmd, const float* __restrict__ Wocoord,
                      __hip_bfloat16* __restrict__ Wr2)
{
  const int flat = blockIdx.x*256 + threadIdx.x;   // 288 blocks: 9*16*64*8 = 73728
  const int j   = flat & 7;
  const int l   = (flat >> 3) & 63;
  const int kc  = (flat >> 9) & 15;
  const int tn  = flat >> 13;
  const int row = tn*16 + (l & 15);
  const int d   = kc*32 + ((l >> 4) & 3)*8 + j;
  float v = 0.f;
  if (row < 128){
    v = Whr[row*DM + d];
  } else if (row < 142){
    const int k = row - 128;
    float a = 0.f;
    for (int p=0; p<PR; ++p){
      float wo = (k < 6) ? Wocmd[k*PR + p] : Wocoord[(k-6)*134 + p];
      a += ln_g[p] * wo * Whr[p*DM + d];
    }
    v = a;
  }
  Wr2[flat] = __float2bfloat16(v);
}

// ================= prep 4: S1[k] = sum_p g_p*Wout[k][p]; S2[k] = sum_p b_p*Wout[k][p] + bout[k]
__global__ void k_s12(const float* __restrict__ ln_g, const float* __restrict__ ln_b,
                      const float* __restrict__ Wocmd, const float* __restrict__ Wocoord,
                      const float* __restrict__ bocmd, const float* __restrict__ bocoord,
                      float* __restrict__ S12)
{
  const int t = threadIdx.x;   // 64, use t<14
  if (t >= 14) return;
  float s1=0.f, s2=0.f;
  for (int p=0;p<PR;++p){
    float wo = (t < 6) ? Wocmd[t*PR + p] : Wocoord[(t-6)*134 + p];
    s1 += ln_g[p]*wo;
    s2 += ln_b[p]*wo;
  }
  s2 += (t < 6) ? bocmd[t] : bocoord[t-6];
  S12[t] = s1; S12[16+t] = s2;
}

// ================= prep 5: ctxT[g][256 batches] = b_ih+b_hh+b_fold + ctx[b]·W_ih[g,512:] ====
__global__ void k_ctxT(const float* __restrict__ context, const float* __restrict__ W_ih,
                       const float* __restrict__ b_ih, const float* __restrict__ b_hh,
                       const float* __restrict__ b_fold, float* __restrict__ ctxT)
{
  const int g = blockIdx.x;      // 2048
  const int b = threadIdx.x;     // 256
  float a = b_ih[g] + b_hh[g] + b_fold[g];
  const float4* cp = reinterpret_cast<const float4*>(context + b*LAT);
  const float4* wp = reinterpret_cast<const float4*>(W_ih + g*640 + DM);
  #pragma unroll 8
  for (int q=0;q<LAT/4;++q){
    float4 c = cp[q], w = wp[q];
    a += c.x*w.x + c.y*w.y + c.z*w.z + c.w*w.w;
  }
  ctxT[g*256 + b] = a;
}

// ================= fused MFMA LSTM scan: 16 blocks x 16 batches, 8 waves ====================
__global__ __launch_bounds__(512)
void k_scan(const float* __restrict__ x_std,
            const float* __restrict__ ctxT,
            const __hip_bfloat16* __restrict__ Bp,
            const __hip_bfloat16* __restrict__ Wr2,
            const float* __restrict__ S12,
            const float* __restrict__ W_out_coord,
            float* __restrict__ out_cmd, float* __restrict__ out_coord)
{
  const int tid = threadIdx.x;
  const int w   = tid >> 6;        // wave 0..7
  const int l   = tid & 63;
  const int l15 = l & 15;
  const int lq  = l >> 4;          // 0..3
  const int b0  = blockIdx.x * 16; // global batch base

  __shared__ __align__(16) __hip_bfloat16 A_lds[16*168];   // [batch][k]: 0..128 h, 128..144 x, 144..160 zero, pad
  __shared__ __align__(16) __hip_bfloat16 HF_lds[16*520];  // [batch][d=512 +8 pad]
  __shared__ float s_red[8*16*2];
  __shared__ float s_mu[16], s_rs[16];

  // ---- init ----
  for (int i = tid; i < 16*168/2; i += 512) reinterpret_cast<unsigned*>(A_lds)[i] = 0u;
  __syncthreads();
  if (tid < 256){
    int b = tid >> 4, c = tid & 15;
    A_lds[b*168 + 128 + c] = __float2bfloat16(x_std[(b0+b)*S_*16 + c]);  // s = 0
  }

  float S1k = 0.f, S2k = 0.f, W2c[6] = {0.f,0.f,0.f,0.f,0.f,0.f};
  if (w == 0 && l15 < 14){
    S1k = S12[l15]; S2k = S12[16 + l15];
    if (l15 >= 6){
      #pragma unroll
      for (int c=0;c<6;++c) W2c[c] = W_out_coord[(l15-6)*134 + 128 + c];
    }
  }

  // C-init (ctx) resident in registers: ctxr[q][gt], element r = batch lq*4+r
  f32x4 ctxr[4][4];
  #pragma unroll
  for (int q=0;q<4;++q){
    const int dt = w*4 + q;
    #pragma unroll
    for (int gt=0;gt<4;++gt){
      const int g = gt*512 + dt*16 + l15;
      ctxr[q][gt] = *reinterpret_cast<const f32x4*>(ctxT + g*256 + b0 + lq*4);
    }
  }

  float c_st[4][4];
  #pragma unroll
  for (int q=0;q<4;++q)
    #pragma unroll
    for (int r=0;r<4;++r) c_st[q][r] = 0.f;

  __syncthreads();

  const f32x4 zz = {0.f, 0.f, 0.f, 0.f};

  for (int s = 0; s < S_; ++s){
    // ======== Phase G: gates = ctx + A(16x160)·B^T, activations, h_full -> LDS ========
    bf16x8 afr[5];
    #pragma unroll
    for (int kc=0;kc<5;++kc)
      afr[kc] = ldg8(&A_lds[l15*168 + kc*32 + lq*8]);

    #pragma unroll
    for (int q=0;q<4;++q){
      const int dt = w*4 + q;
      f32x4 acc[4];
      #pragma unroll
      for (int gt=0;gt<4;++gt) acc[gt] = ctxr[q][gt];
      #pragma unroll
      for (int kc=0;kc<5;++kc){
        #pragma unroll
        for (int gt=0;gt<4;++gt){
          const int n = gt*32 + dt;                       // N-tile index
          bf16x8 bfr = ldg8(Bp + ((n*5 + kc)*64 + l)*8);  // fully coalesced 1KB/wave
          acc[gt] = __builtin_amdgcn_mfma_f32_16x16x32_bf16(afr[kc], bfr, acc[gt], 0, 0, 0);
        }
      }
      #pragma unroll
      for (int r=0;r<4;++r){
        float iv = sigf(acc[0][r]);
        float fv = sigf(acc[1][r]);
        float gv = tanhft(acc[2][r]);
        float ov = sigf(acc[3][r]);
        float cc = fv*c_st[q][r] + iv*gv;
        c_st[q][r] = cc;
        HF_lds[(lq*4 + r)*520 + dt*16 + l15] = __float2bfloat16(ov*tanhft(cc));
      }
    }
    __syncthreads();  // B1

    // ======== Phase R: [h | P] = h_full(16x512) · Wr2^T ; LN partials; x prefetch ========
    f32x4 accA = zz, accB = zz, acc3A = zz, acc3B = zz;
    #pragma unroll
    for (int kc=0;kc<16;++kc){
      bf16x8 a2 = ldg8(&HF_lds[l15*520 + kc*32 + lq*8]);
      bf16x8 b2 = ldg8(Wr2 + ((w*16 + kc)*64 + l)*8);
      if (kc & 1) accB = __builtin_amdgcn_mfma_f32_16x16x32_bf16(a2, b2, accB, 0,0,0);
      else        accA = __builtin_amdgcn_mfma_f32_16x16x32_bf16(a2, b2, accA, 0,0,0);
      if (w == 0){
        bf16x8 b3 = ldg8(Wr2 + ((8*16 + kc)*64 + l)*8);
        if (kc & 1) acc3B = __builtin_amdgcn_mfma_f32_16x16x32_bf16(a2, b3, acc3B, 0,0,0);
        else        acc3A = __builtin_amdgcn_mfma_f32_16x16x32_bf16(a2, b3, acc3A, 0,0,0);
      }
    }
    f32x4 acc2 = accA + accB;
    f32x4 acc3 = acc3A + acc3B;

    // LN partial sums over this wave's 16 p's (butterfly over lane bits 0..3)
    float sm[4], sq[4];
    #pragma unroll
    for (int r=0;r<4;++r){
      float v = acc2[r];
      sm[r] = v; sq[r] = v*v;
      #pragma unroll
      for (int m=1;m<16;m<<=1){
        sm[r] += __shfl_xor(sm[r], m);
        sq[r] += __shfl_xor(sq[r], m);
      }
    }
    if (l15 == 0){
      #pragma unroll
      for (int r=0;r<4;++r){
        s_red[(w*16 + lq*4 + r)*2 + 0] = sm[r];
        s_red[(w*16 + lq*4 + r)*2 + 1] = sq[r];
      }
    }
    // x prefetch for step s+1
    if (s+1 < S_ && tid < 256){
      int b = tid >> 4, c = tid & 15;
      A_lds[b*168 + 128 + c] = __float2bfloat16(x_std[((b0+b)*S_ + s+1)*16 + c]);
    }
    __syncthreads();  // B2

    // ======== Phase F: finalize mu / rstd (16 threads) ========
    if (tid < 16){
      float m = 0.f, v = 0.f;
      #pragma unroll
      for (int ww=0; ww<8; ++ww){
        m += s_red[(ww*16 + tid)*2 + 0];
        v += s_red[(ww*16 + tid)*2 + 1];
      }
      m *= (1.f/128.f);
      v = v*(1.f/128.f) - m*m;
      s_mu[tid] = m;
      s_rs[tid] = rsqrtf(v + 1e-5f);
    }
    __syncthreads();  // B3

    // ======== Phase E: RAW h -> A_lds (recurrent state) ; heads (wave 0) -> global ========
    #pragma unroll
    for (int r=0;r<4;++r){
      const int b = lq*4 + r;
      A_lds[b*168 + w*16 + l15] = __float2bfloat16(acc2[r]);   // raw h, NOT LayerNormed
    }
    if (w == 0){
      #pragma unroll
      for (int r=0;r<4;++r){
        const int b = lq*4 + r;
        float val = s_rs[b]*(acc3[r] - s_mu[b]*S1k) + S2k;
        // broadcast finalized cmd values within each 16-lane group
        float c0v = __shfl(val, (l & 48) + 0);
        float c1v = __shfl(val, (l & 48) + 1);
        float c2v = __shfl(val, (l & 48) + 2);
        float c3v = __shfl(val, (l & 48) + 3);
        float c4v = __shfl(val, (l & 48) + 4);
        float c5v = __shfl(val, (l & 48) + 5);
        if (l15 < 6){
          out_cmd[((b0+b)*S_ + s)*6 + l15] = val;
        } else if (l15 < 14){
          val += c0v*W2c[0] + c1v*W2c[1] + c2v*W2c[2]
               + c3v*W2c[3] + c4v*W2c[4] + c5v*W2c[5];
          out_coord[((b0+b)*S_ + s)*8 + (l15-6)] = val;
        }
      }
    }
    __syncthreads();  // B4 (protects A_lds/HF/s_* for next iteration)
  }
}

extern "C" void kernel_launch(void* const* d_in, const int* in_sizes, int n_in,
                              void* d_out, int out_size, void* d_ws, size_t ws_size,
                              hipStream_t stream)
{
  const float* x_std       = (const float*)d_in[0];
  const float* context     = (const float*)d_in[1];
  const float* W_cmd       = (const float*)d_in[2];
  const float* b_cmd       = (const float*)d_in[3];
  const float* W_coord     = (const float*)d_in[4];
  const float* b_coord     = (const float*)d_in[5];
  const float* W_head      = (const float*)d_in[6];
  const float* b_head      = (const float*)d_in[7];
  const float* W_ih        = (const float*)d_in[8];
  const float* W_hh        = (const float*)d_in[9];
  const float* W_hr        = (const float*)d_in[10];
  const float* b_ih        = (const float*)d_in[11];
  const float* b_hh        = (const float*)d_in[12];
  const float* ln_g        = (const float*)d_in[13];
  const float* ln_b        = (const float*)d_in[14];
  const float* W_out_cmd   = (const float*)d_in[15];
  const float* b_out_cmd   = (const float*)d_in[16];
  const float* W_out_coord = (const float*)d_in[17];
  const float* b_out_coord = (const float*)d_in[18];

  float* out = (float*)d_out;
  char*  ws  = (char*)d_ws;

  // layout (W_comb overlaid by ctxT after k_bp consumes it):
  __hip_bfloat16* Bp   = (__hip_bfloat16*)(ws);             // 655360 B
  __hip_bfloat16* Wr2  = (__hip_bfloat16*)(ws + 655360);    // 147456 B -> 802816
  float* b_fold        = (float*)(ws + 802816);             // 8192   -> 811008
  float* S12           = (float*)(ws + 811008);             // 256    -> 811264
  float* W_comb        = (float*)(ws + 811264);             // 131072 (dead after k_bp)
  float* ctxT          = (float*)(ws + 811264);             // 2097152 -> 2908416 total (~2.77 MB)

  k_fold<<<dim3(G4), dim3(64), 0, stream>>>(W_ih, W_cmd, b_cmd, W_coord, b_coord,
                                            W_head, b_head, W_comb, b_fold);
  k_bp<<<dim3(1280), dim3(256), 0, stream>>>(W_hh, W_comb, Bp);
  k_wr2<<<dim3(288), dim3(256), 0, stream>>>(W_hr, ln_g, W_out_cmd, W_out_coord, Wr2);
  k_s12<<<dim3(1), dim3(64), 0, stream>>>(ln_g, ln_b, W_out_cmd, W_out_coord,
                                          b_out_cmd, b_out_coord, S12);
  k_ctxT<<<dim3(G4), dim3(256), 0, stream>>>(context, W_ih, b_ih, b_hh, b_fold, ctxT);
  k_scan<<<dim3(16), dim3(512), 0, stream>>>(x_std, ctxT, Bp, Wr2, S12,
                                             W_out_coord, out, out + B_*S_*6);
}

// Round 5
// 2966.669 us; speedup vs baseline: 23.8597x; 2.1021x over previous
//
#include <hip/hip_runtime.h>
#include <hip/hip_bf16.h>
#include <stdint.h>

#define B_   256
#define S_   256
#define DM   512
#define G4   2048
#define LAT  128
#define PR   128

typedef __bf16 bf16x8 __attribute__((ext_vector_type(8)));
typedef float  f32x4  __attribute__((ext_vector_type(4)));

__device__ __forceinline__ bf16x8 ldg8(const __hip_bfloat16* p){
  uint4 v = *reinterpret_cast<const uint4*>(p);
  return __builtin_bit_cast(bf16x8, v);
}
__device__ __forceinline__ float sigf(float x){ return 1.f/(1.f+__expf(-x)); }
__device__ __forceinline__ float tanhft(float x){ return 1.f - 2.f/(__expf(2.f*x)+1.f); }
__device__ __forceinline__ unsigned char f2fp8(float x){
  return (unsigned char)(__builtin_amdgcn_cvt_pk_fp8_f32(x, x, 0, false) & 0xff);
}

// ================= prep 1: W_comb[2048][16] = W_ih[:, :512] · Wcat, + folded x-bias ===========
__global__ void k_fold(const float* __restrict__ W_ih,
                       const float* __restrict__ W_cmd, const float* __restrict__ b_cmd,
                       const float* __restrict__ W_coord, const float* __restrict__ b_coord,
                       const float* __restrict__ W_head, const float* __restrict__ b_head,
                       float* __restrict__ W_comb, float* __restrict__ b_fold)
{
  const int g = blockIdx.x;      // 2048
  const int lane = threadIdx.x;  // 64
  float p[17];
  #pragma unroll
  for (int k=0;k<17;++k) p[k]=0.f;
  for (int d = lane; d < DM; d += 64){
    float w = W_ih[g*640 + d];
    #pragma unroll
    for (int c=0;c<6;++c)  p[c]    += w * W_cmd[d*6+c];
    #pragma unroll
    for (int c=0;c<8;++c)  p[6+c]  += w * W_coord[d*8+c];
    p[14] += w * W_head[d*2+0];
    p[15] += w * W_head[d*2+1];
    p[16] += w * (b_cmd[d] + b_coord[d] + b_head[d]);
  }
  #pragma unroll
  for (int k=0;k<17;++k){
    #pragma unroll
    for (int off=32; off>0; off>>=1) p[k] += __shfl_xor(p[k], off);
  }
  if (lane == 0){
    #pragma unroll
    for (int k=0;k<16;++k) W_comb[g*16+k] = p[k];
    b_fold[g] = p[16];
  }
}

// ================= prep 2: gate-B fp8, scaled x16, fragment-linear ==========================
// Bp[((n*5+kc)*64 + l)*8 + j] = fp8(16 * Wrow[g][k]), g=n*16+(l&15), k=kc*32+((l>>4)&3)*8+j
__global__ void k_bp(const float* __restrict__ Whh, const float* __restrict__ W_comb,
                     unsigned char* __restrict__ Bp)
{
  const int flat = blockIdx.x*256 + threadIdx.x;   // 1280 blocks -> 327680
  const int j   = flat & 7;
  const int l   = (flat >> 3) & 63;
  const int idx = flat >> 9;                        // n*5 + kc
  const int n   = idx / 5;
  const int kc  = idx - n*5;
  const int g   = n*16 + (l & 15);
  const int k   = kc*32 + ((l >> 4) & 3)*8 + j;
  float v = (k < 128) ? Whh[g*PR + k] : ((k < 144) ? W_comb[g*16 + (k-128)] : 0.f);
  Bp[flat] = f2fp8(16.f * v);
}

// ================= prep 3: W_hr bf16 fragment-linear (8 tiles) ==============================
__global__ void k_wr2(const float* __restrict__ Whr, __hip_bfloat16* __restrict__ Wr2)
{
  const int flat = blockIdx.x*256 + threadIdx.x;   // 256 blocks: 8*16*64*8 = 65536
  const int j   = flat & 7;
  const int l   = (flat >> 3) & 63;
  const int kc  = (flat >> 9) & 15;
  const int tn  = flat >> 13;                       // 0..7
  const int row = tn*16 + (l & 15);                 // p < 128
  const int d   = kc*32 + ((l >> 4) & 3)*8 + j;
  Wr2[flat] = __float2bfloat16(Whr[row*DM + d]);
}

// ================= prep 4: folded head weights W~[t][p] (coord absorbs cmd), + bias =========
__global__ void k_wout(const float* __restrict__ Wocmd, const float* __restrict__ Wocoord,
                       const float* __restrict__ bocmd, const float* __restrict__ bocoord,
                       __hip_bfloat16* __restrict__ Wh, float* __restrict__ btil)
{
  if (blockIdx.x == 8){
    const int t = threadIdx.x;
    if (t < 16){
      float bv = 0.f;
      if (t < 6) bv = bocmd[t];
      else if (t < 14){
        bv = bocoord[t-6];
        for (int k=0;k<6;++k) bv += Wocoord[(t-6)*134 + 128 + k]*bocmd[k];
      }
      btil[t] = bv;
    }
    return;
  }
  const int flat = blockIdx.x*256 + threadIdx.x;   // 0..2047
  const int j  = flat & 7;
  const int l  = (flat >> 3) & 63;
  const int kc = flat >> 9;                         // 0..3
  const int t  = l & 15;
  const int p  = kc*32 + ((l >> 4) & 3)*8 + j;
  float v = 0.f;
  if (t < 6) v = Wocmd[t*PR + p];
  else if (t < 14){
    v = Wocoord[(t-6)*134 + p];
    for (int k=0;k<6;++k) v += Wocoord[(t-6)*134 + 128 + k]*Wocmd[k*PR + p];
  }
  Wh[flat] = __float2bfloat16(v);
}

// ================= prep 5: ctxT[g][256 batches] = b_ih+b_hh+b_fold + ctx[b]·W_ih[g,512:] ====
__global__ void k_ctxT(const float* __restrict__ context, const float* __restrict__ W_ih,
                       const float* __restrict__ b_ih, const float* __restrict__ b_hh,
                       const float* __restrict__ b_fold, float* __restrict__ ctxT)
{
  const int g = blockIdx.x;      // 2048
  const int b = threadIdx.x;     // 256
  float a = b_ih[g] + b_hh[g] + b_fold[g];
  const float4* cp = reinterpret_cast<const float4*>(context + b*LAT);
  const float4* wp = reinterpret_cast<const float4*>(W_ih + g*640 + DM);
  #pragma unroll 8
  for (int q=0;q<LAT/4;++q){
    float4 c = cp[q], w = wp[q];
    a += c.x*w.x + c.y*w.y + c.z*w.z + c.w*w.w;
  }
  ctxT[g*256 + b] = a;
}

// ================= fused MFMA LSTM scan: weights-in-registers (fp8 gates) ====================
__global__ __launch_bounds__(512)
void k_scan(const float* __restrict__ x_std,
            const float* __restrict__ ctxT,
            const unsigned char* __restrict__ Bp,
            const __hip_bfloat16* __restrict__ Wr2,
            const __hip_bfloat16* __restrict__ Wh,
            const float* __restrict__ btil,
            const float* __restrict__ ln_g, const float* __restrict__ ln_b,
            float* __restrict__ out_cmd, float* __restrict__ out_coord)
{
  const int tid = threadIdx.x;
  const int w   = tid >> 6;        // wave 0..7
  const int l   = tid & 63;
  const int l15 = l & 15;
  const int lq  = l >> 4;          // 0..3
  const int b0  = blockIdx.x * 16;

  __shared__ __align__(16) float ctx_lds[G4*16];            // 128 KB  [g][b 0..15]
  __shared__ __align__(16) __hip_bfloat16 HF[16*520];       // 16.25 KB [b][d] stride 520
  __shared__ __align__(8)  unsigned char  A8[16*168];       // 2.6 KB  [b][k] fp8 (h|x|0)
  __shared__ __align__(16) __hip_bfloat16 HN[16*136];       // 4.25 KB [b][p]
  __shared__ float s_red[256];
  __shared__ float s_mu[16], s_rs[16];

  // ---- gate weights -> registers (fp8, once) ----
  long bp[4][4][5];
  #pragma unroll
  for (int dtl=0; dtl<4; ++dtl)
    #pragma unroll
    for (int gt=0; gt<4; ++gt)
      #pragma unroll
      for (int kc=0; kc<5; ++kc){
        const int n = gt*32 + w*4 + dtl;
        bp[dtl][gt][kc] = *reinterpret_cast<const long*>(Bp + ((n*5 + kc)*64 + l)*8);
      }

  // ---- ctx slice -> LDS (f32) ----
  for (int i = tid; i < G4*16; i += 512){
    const int g = i >> 4, b = i & 15;
    ctx_lds[i] = ctxT[g*256 + b0 + b];
  }
  // ---- A8 zero ----
  for (int i = tid; i < 16*168/4; i += 512) reinterpret_cast<unsigned*>(A8)[i] = 0u;
  __syncthreads();
  if (tid < 256){
    const int b = tid >> 4, c = tid & 15;
    A8[b*168 + 128 + c] = f2fp8(x_std[(b0+b)*S_*16 + c]);   // s = 0
  }

  const float lng = ln_g[w*16 + l15];
  const float lnb = ln_b[w*16 + l15];
  const float bb  = (l15 < 14) ? btil[l15] : 0.f;

  float c_st[4][4];
  #pragma unroll
  for (int q=0;q<4;++q)
    #pragma unroll
    for (int r=0;r<4;++r) c_st[q][r] = 0.f;

  __syncthreads();

  const f32x4 zz = {0.f, 0.f, 0.f, 0.f};
  const int a_off = l15*168 + lq*8;   // + kc*32

  for (int s = 0; s < S_; ++s){
    // ======== deferred heads for step s-1 (wave 7) ========
    if (w == 7 && s > 0){
      f32x4 hd = zz;
      #pragma unroll
      for (int kc=0;kc<4;++kc){
        bf16x8 ha = ldg8(&HN[l15*136 + kc*32 + lq*8]);
        bf16x8 hb = ldg8(Wh + ((kc*64 + l)*8));
        hd = __builtin_amdgcn_mfma_f32_16x16x32_bf16(ha, hb, hd, 0,0,0);
      }
      #pragma unroll
      for (int r=0;r<4;++r){
        const int b = b0 + lq*4 + r;
        const float v = hd[r] + bb;
        if (l15 < 6)       out_cmd[(b*S_ + (s-1))*6 + l15] = v;
        else if (l15 < 14) out_coord[(b*S_ + (s-1))*8 + (l15-6)] = v;
      }
    }

    // ======== Phase G: gates (fp8 MFMA, weights in regs), cell update, h_full -> LDS ========
    long afr[5];
    #pragma unroll
    for (int kc=0;kc<5;++kc)
      afr[kc] = *reinterpret_cast<const long*>(&A8[a_off + kc*32]);

    #pragma unroll
    for (int dtl=0; dtl<4; ++dtl){
      const int dt = w*4 + dtl;
      f32x4 az[4] = {zz, zz, zz, zz};
      #pragma unroll
      for (int kc=0;kc<5;++kc)
        #pragma unroll
        for (int gt=0; gt<4; ++gt)
          az[gt] = __builtin_amdgcn_mfma_f32_16x16x32_fp8_fp8(afr[kc], bp[dtl][gt][kc], az[gt], 0,0,0);
      f32x4 cv[4];
      #pragma unroll
      for (int gt=0; gt<4; ++gt)
        cv[gt] = *reinterpret_cast<const f32x4*>(&ctx_lds[(gt*512 + dt*16 + l15)*16 + lq*4]);
      #pragma unroll
      for (int r=0;r<4;++r){
        const float iv = sigf  (cv[0][r] + az[0][r]*0.0625f);
        const float fv = sigf  (cv[1][r] + az[1][r]*0.0625f);
        const float gv = tanhft(cv[2][r] + az[2][r]*0.0625f);
        const float ov = sigf  (cv[3][r] + az[3][r]*0.0625f);
        const float cc = fv*c_st[dtl][r] + iv*gv;
        c_st[dtl][r] = cc;
        HF[(lq*4 + r)*520 + dt*16 + l15] = __float2bfloat16(ov*tanhft(cc));
      }
    }
    __syncthreads();  // B1

    // ======== Phase R: h = h_full · W_hr^T (bf16 stream, 4-group pipelined) ========
    f32x4 aA = zz, aB = zz;
    {
      bf16x8 wva[4], wvb[4];
      #pragma unroll
      for (int kk=0;kk<4;++kk) wva[kk] = ldg8(Wr2 + ((w*16 +  0 + kk)*64 + l)*8);
      #pragma unroll
      for (int kk=0;kk<4;++kk) wvb[kk] = ldg8(Wr2 + ((w*16 +  4 + kk)*64 + l)*8);
      #pragma unroll
      for (int kk=0;kk<4;++kk){
        bf16x8 a2 = ldg8(&HF[l15*520 + (0+kk)*32 + lq*8]);
        if (kk&1) aB = __builtin_amdgcn_mfma_f32_16x16x32_bf16(a2, wva[kk], aB, 0,0,0);
        else      aA = __builtin_amdgcn_mfma_f32_16x16x32_bf16(a2, wva[kk], aA, 0,0,0);
      }
      #pragma unroll
      for (int kk=0;kk<4;++kk) wva[kk] = ldg8(Wr2 + ((w*16 +  8 + kk)*64 + l)*8);
      #pragma unroll
      for (int kk=0;kk<4;++kk){
        bf16x8 a2 = ldg8(&HF[l15*520 + (4+kk)*32 + lq*8]);
        if (kk&1) aB = __builtin_amdgcn_mfma_f32_16x16x32_bf16(a2, wvb[kk], aB, 0,0,0);
        else      aA = __builtin_amdgcn_mfma_f32_16x16x32_bf16(a2, wvb[kk], aA, 0,0,0);
      }
      #pragma unroll
      for (int kk=0;kk<4;++kk) wvb[kk] = ldg8(Wr2 + ((w*16 + 12 + kk)*64 + l)*8);
      #pragma unroll
      for (int kk=0;kk<4;++kk){
        bf16x8 a2 = ldg8(&HF[l15*520 + (8+kk)*32 + lq*8]);
        if (kk&1) aB = __builtin_amdgcn_mfma_f32_16x16x32_bf16(a2, wva[kk], aB, 0,0,0);
        else      aA = __builtin_amdgcn_mfma_f32_16x16x32_bf16(a2, wva[kk], aA, 0,0,0);
      }
      #pragma unroll
      for (int kk=0;kk<4;++kk){
        bf16x8 a2 = ldg8(&HF[l15*520 + (12+kk)*32 + lq*8]);
        if (kk&1) aB = __builtin_amdgcn_mfma_f32_16x16x32_bf16(a2, wvb[kk], aB, 0,0,0);
        else      aA = __builtin_amdgcn_mfma_f32_16x16x32_bf16(a2, wvb[kk], aA, 0,0,0);
      }
    }
    f32x4 acc2 = aA + aB;

    // LN partials (butterfly over lane bits 0..3)
    float sm[4], sq[4];
    #pragma unroll
    for (int r=0;r<4;++r){
      float v = acc2[r];
      sm[r] = v; sq[r] = v*v;
      #pragma unroll
      for (int m=1;m<16;m<<=1){
        sm[r] += __shfl_xor(sm[r], m);
        sq[r] += __shfl_xor(sq[r], m);
      }
    }
    if (l15 == 0){
      #pragma unroll
      for (int r=0;r<4;++r){
        s_red[(w*16 + lq*4 + r)*2 + 0] = sm[r];
        s_red[(w*16 + lq*4 + r)*2 + 1] = sq[r];
      }
    }
    // x prefetch for step s+1
    if (s+1 < S_ && tid < 256){
      const int b = tid >> 4, c = tid & 15;
      A8[b*168 + 128 + c] = f2fp8(x_std[((b0+b)*S_ + s+1)*16 + c]);
    }
    __syncthreads();  // B2

    // ======== Phase F: finalize mu / rstd ========
    if (tid < 16){
      float m = 0.f, v = 0.f;
      #pragma unroll
      for (int ww=0; ww<8; ++ww){
        m += s_red[(ww*16 + tid)*2 + 0];
        v += s_red[(ww*16 + tid)*2 + 1];
      }
      m *= (1.f/128.f);
      v = v*(1.f/128.f) - m*m;
      s_mu[tid] = m;
      s_rs[tid] = rsqrtf(v + 1e-5f);
    }
    __syncthreads();  // B3

    // ======== Phase E: raw h -> A8 (fp8, recurrent); hn -> HN (bf16, for heads) ========
    #pragma unroll
    for (int r=0;r<4;++r){
      const int b = lq*4 + r;
      const float h  = acc2[r];
      const float hn = (h - s_mu[b]) * s_rs[b] * lng + lnb;
      HN[b*136 + w*16 + l15] = __float2bfloat16(hn);
      A8[b*168 + w*16 + l15] = f2fp8(h);
    }
    __syncthreads();  // B4
  }

  // ======== epilogue: heads for s = S_-1 (wave 7) ========
  if (w == 7){
    f32x4 hd = zz;
    #pragma unroll
    for (int kc=0;kc<4;++kc){
      bf16x8 ha = ldg8(&HN[l15*136 + kc*32 + lq*8]);
      bf16x8 hb = ldg8(Wh + ((kc*64 + l)*8));
      hd = __builtin_amdgcn_mfma_f32_16x16x32_bf16(ha, hb, hd, 0,0,0);
    }
    #pragma unroll
    for (int r=0;r<4;++r){
      const int b = b0 + lq*4 + r;
      const float v = hd[r] + bb;
      if (l15 < 6)       out_cmd[(b*S_ + (S_-1))*6 + l15] = v;
      else if (l15 < 14) out_coord[(b*S_ + (S_-1))*8 + (l15-6)] = v;
    }
  }
}

extern "C" void kernel_launch(void* const* d_in, const int* in_sizes, int n_in,
                              void* d_out, int out_size, void* d_ws, size_t ws_size,
                              hipStream_t stream)
{
  const float* x_std       = (const float*)d_in[0];
  const float* context     = (const float*)d_in[1];
  const float* W_cmd       = (const float*)d_in[2];
  const float* b_cmd       = (const float*)d_in[3];
  const float* W_coord     = (const float*)d_in[4];
  const float* b_coord     = (const float*)d_in[5];
  const float* W_head      = (const float*)d_in[6];
  const float* b_head      = (const float*)d_in[7];
  const float* W_ih        = (const float*)d_in[8];
  const float* W_hh        = (const float*)d_in[9];
  const float* W_hr        = (const float*)d_in[10];
  const float* b_ih        = (const float*)d_in[11];
  const float* b_hh        = (const float*)d_in[12];
  const float* ln_g        = (const float*)d_in[13];
  const float* ln_b        = (const float*)d_in[14];
  const float* W_out_cmd   = (const float*)d_in[15];
  const float* b_out_cmd   = (const float*)d_in[16];
  const float* W_out_coord = (const float*)d_in[17];
  const float* b_out_coord = (const float*)d_in[18];

  float* out = (float*)d_out;
  char*  ws  = (char*)d_ws;

  unsigned char*  Bp   = (unsigned char*)(ws);              // 327680 B
  __hip_bfloat16* Wr2  = (__hip_bfloat16*)(ws + 327680);    // 131072 -> 458752
  __hip_bfloat16* Wh   = (__hip_bfloat16*)(ws + 458752);    // 4096   -> 462848
  float* btil          = (float*)(ws + 462848);             // 64     -> 462912
  float* b_fold        = (float*)(ws + 462912);             // 8192   -> 471104
  float* W_comb        = (float*)(ws + 471104);             // 131072 (dead after k_bp)
  float* ctxT          = (float*)(ws + 471104 + 131072);    // 2 MB -> 2699328 total (~2.6 MB)

  k_fold<<<dim3(G4), dim3(64), 0, stream>>>(W_ih, W_cmd, b_cmd, W_coord, b_coord,
                                            W_head, b_head, W_comb, b_fold);
  k_bp<<<dim3(1280), dim3(256), 0, stream>>>(W_hh, W_comb, Bp);
  k_wr2<<<dim3(256), dim3(256), 0, stream>>>(W_hr, Wr2);
  k_wout<<<dim3(9), dim3(256), 0, stream>>>(W_out_cmd, W_out_coord, b_out_cmd, b_out_coord,
                                            Wh, btil);
  k_ctxT<<<dim3(G4), dim3(256), 0, stream>>>(context, W_ih, b_ih, b_hh, b_fold, ctxT);
  k_scan<<<dim3(16), dim3(512), 0, stream>>>(x_std, ctxT, Bp, Wr2, Wh, btil, ln_g, ln_b,
                                             out, out + B_*S_*6);
}

// Round 6
// 2764.120 us; speedup vs baseline: 25.6081x; 1.0733x over previous
//
#include <hip/hip_runtime.h>
#include <hip/hip_bf16.h>
#include <stdint.h>

#define B_   256
#define S_   256
#define DM   512
#define G4   2048
#define LAT  128
#define PR   128

typedef __bf16 bf16x8 __attribute__((ext_vector_type(8)));
typedef float  f32x4  __attribute__((ext_vector_type(4)));

__device__ __forceinline__ bf16x8 ldg8(const __hip_bfloat16* p){
  uint4 v = *reinterpret_cast<const uint4*>(p);
  return __builtin_bit_cast(bf16x8, v);
}
__device__ __forceinline__ float sigf(float x){ return 1.f/(1.f+__expf(-x)); }
__device__ __forceinline__ float tanhft(float x){ return 1.f - 2.f/(__expf(2.f*x)+1.f); }
__device__ __forceinline__ unsigned char f2fp8(float x){
  return (unsigned char)(__builtin_amdgcn_cvt_pk_fp8_f32(x, x, 0, false) & 0xff);
}

// ================= prep 1: W_comb[2048][16] = W_ih[:, :512] · Wcat, + folded x-bias ===========
__global__ void k_fold(const float* __restrict__ W_ih,
                       const float* __restrict__ W_cmd, const float* __restrict__ b_cmd,
                       const float* __restrict__ W_coord, const float* __restrict__ b_coord,
                       const float* __restrict__ W_head, const float* __restrict__ b_head,
                       float* __restrict__ W_comb, float* __restrict__ b_fold)
{
  const int g = blockIdx.x;      // 2048
  const int lane = threadIdx.x;  // 64
  float p[17];
  #pragma unroll
  for (int k=0;k<17;++k) p[k]=0.f;
  for (int d = lane; d < DM; d += 64){
    float w = W_ih[g*640 + d];
    #pragma unroll
    for (int c=0;c<6;++c)  p[c]    += w * W_cmd[d*6+c];
    #pragma unroll
    for (int c=0;c<8;++c)  p[6+c]  += w * W_coord[d*8+c];
    p[14] += w * W_head[d*2+0];
    p[15] += w * W_head[d*2+1];
    p[16] += w * (b_cmd[d] + b_coord[d] + b_head[d]);
  }
  #pragma unroll
  for (int k=0;k<17;++k){
    #pragma unroll
    for (int off=32; off>0; off>>=1) p[k] += __shfl_xor(p[k], off);
  }
  if (lane == 0){
    #pragma unroll
    for (int k=0;k<16;++k) W_comb[g*16+k] = p[k];
    b_fold[g] = p[16];
  }
}

// ================= prep 2: gate-B fp8, scaled x16, fragment-linear ==========================
// Bp[((n*5+kc)*64 + l)*8 + j] = fp8(16 * Wrow[g][k]), g=n*16+(l&15), k=kc*32+((l>>4)&3)*8+j
__global__ void k_bp(const float* __restrict__ Whh, const float* __restrict__ W_comb,
                     unsigned char* __restrict__ Bp)
{
  const int flat = blockIdx.x*256 + threadIdx.x;   // 1280 blocks -> 327680
  const int j   = flat & 7;
  const int l   = (flat >> 3) & 63;
  const int idx = flat >> 9;                        // n*5 + kc
  const int n   = idx / 5;
  const int kc  = idx - n*5;
  const int g   = n*16 + (l & 15);
  const int k   = kc*32 + ((l >> 4) & 3)*8 + j;
  float v = (k < 128) ? Whh[g*PR + k] : ((k < 144) ? W_comb[g*16 + (k-128)] : 0.f);
  Bp[flat] = f2fp8(16.f * v);
}

// ================= prep 3: W_hr bf16 fragment-linear (8 tiles) ==============================
__global__ void k_wr2(const float* __restrict__ Whr, __hip_bfloat16* __restrict__ Wr2)
{
  const int flat = blockIdx.x*256 + threadIdx.x;   // 256 blocks: 8*16*64*8 = 65536
  const int j   = flat & 7;
  const int l   = (flat >> 3) & 63;
  const int kc  = (flat >> 9) & 15;
  const int tn  = flat >> 13;                       // 0..7
  const int row = tn*16 + (l & 15);                 // p < 128
  const int d   = kc*32 + ((l >> 4) & 3)*8 + j;
  Wr2[flat] = __float2bfloat16(Whr[row*DM + d]);
}

// ================= prep 4: folded head weights W~[t][p] (coord absorbs cmd), + bias =========
__global__ void k_wout(const float* __restrict__ Wocmd, const float* __restrict__ Wocoord,
                       const float* __restrict__ bocmd, const float* __restrict__ bocoord,
                       __hip_bfloat16* __restrict__ Wh, float* __restrict__ btil)
{
  if (blockIdx.x == 8){
    const int t = threadIdx.x;
    if (t < 16){
      float bv = 0.f;
      if (t < 6) bv = bocmd[t];
      else if (t < 14){
        bv = bocoord[t-6];
        for (int k=0;k<6;++k) bv += Wocoord[(t-6)*134 + 128 + k]*bocmd[k];
      }
      btil[t] = bv;
    }
    return;
  }
  const int flat = blockIdx.x*256 + threadIdx.x;   // 0..2047
  const int j  = flat & 7;
  const int l  = (flat >> 3) & 63;
  const int kc = flat >> 9;                         // 0..3
  const int t  = l & 15;
  const int p  = kc*32 + ((l >> 4) & 3)*8 + j;
  float v = 0.f;
  if (t < 6) v = Wocmd[t*PR + p];
  else if (t < 14){
    v = Wocoord[(t-6)*134 + p];
    for (int k=0;k<6;++k) v += Wocoord[(t-6)*134 + 128 + k]*Wocmd[k*PR + p];
  }
  Wh[flat] = __float2bfloat16(v);
}

// ================= prep 5: ctxT[g][256 batches] = b_ih+b_hh+b_fold + ctx[b]·W_ih[g,512:] ====
__global__ void k_ctxT(const float* __restrict__ context, const float* __restrict__ W_ih,
                       const float* __restrict__ b_ih, const float* __restrict__ b_hh,
                       const float* __restrict__ b_fold, float* __restrict__ ctxT)
{
  const int g = blockIdx.x;      // 2048
  const int b = threadIdx.x;     // 256
  float a = b_ih[g] + b_hh[g] + b_fold[g];
  const float4* cp = reinterpret_cast<const float4*>(context + b*LAT);
  const float4* wp = reinterpret_cast<const float4*>(W_ih + g*640 + DM);
  #pragma unroll 8
  for (int q=0;q<LAT/4;++q){
    float4 c = cp[q], w = wp[q];
    a += c.x*w.x + c.y*w.y + c.z*w.z + c.w*w.w;
  }
  ctxT[g*256 + b] = a;
}

// ================= fused MFMA LSTM scan: fp8 gate weights split regs(kc0-2)+LDS(kc3-4) ======
__global__ __launch_bounds__(512, 2)
void k_scan(const float* __restrict__ x_std,
            const float* __restrict__ ctxT,
            const unsigned char* __restrict__ Bp,
            const __hip_bfloat16* __restrict__ Wr2,
            const __hip_bfloat16* __restrict__ Wh,
            const float* __restrict__ btil,
            const float* __restrict__ ln_g, const float* __restrict__ ln_b,
            float* __restrict__ out_cmd, float* __restrict__ out_coord)
{
  const int tid = threadIdx.x;
  const int w   = tid >> 6;        // wave 0..7
  const int l   = tid & 63;
  const int l15 = l & 15;
  const int lq  = l >> 4;          // 0..3
  const int b0  = blockIdx.x * 16;

  __shared__ __align__(8)  unsigned char  Bw[G4*64];        // 128 KB: gate-B kc=3,4, frag-linear
  __shared__ __align__(16) __hip_bfloat16 HF[16*520];       // 16.25 KB [b][d] stride 520
  __shared__ __align__(8)  unsigned char  A8[16*168];       // 2.6 KB  [b][k] fp8 (h|x|0)
  __shared__ __align__(16) __hip_bfloat16 HN[16*136];       // 4.25 KB [b][p]
  __shared__ float s_red[256];
  __shared__ float s_mu[16], s_rs[16];

  // ---- gate weights kc=0..2 -> registers (96 VGPR) ----
  long bp[4][4][3];
  #pragma unroll
  for (int dtl=0; dtl<4; ++dtl)
    #pragma unroll
    for (int gt=0; gt<4; ++gt)
      #pragma unroll
      for (int kc=0; kc<3; ++kc){
        const int n = gt*32 + w*4 + dtl;
        bp[dtl][gt][kc] = *reinterpret_cast<const long*>(Bp + ((n*5 + kc)*64 + l)*8);
      }

  // ---- gate weights kc=3,4 -> LDS (lane-linear, conflict-free reads) ----
  {
    const long* Bpl = reinterpret_cast<const long*>(Bp);
    long* Bwl = reinterpret_cast<long*>(Bw);
    for (int i = tid; i < G4*64/8; i += 512){
      const int nn  = i >> 7;
      const int rem = i & 127;
      const int kcl = rem >> 6;
      const int ll  = rem & 63;
      Bwl[i] = Bpl[(nn*5 + 3 + kcl)*64 + ll];
    }
  }

  // ---- ctx -> registers, pre-scaled x16 (fp8 weight scale) ----
  f32x4 ctxr[4][4];
  #pragma unroll
  for (int dtl=0; dtl<4; ++dtl){
    const int dt = w*4 + dtl;
    #pragma unroll
    for (int gt=0; gt<4; ++gt){
      const int g = gt*512 + dt*16 + l15;
      f32x4 c = *reinterpret_cast<const f32x4*>(ctxT + g*256 + b0 + lq*4);
      ctxr[dtl][gt] = c * 16.f;
    }
  }

  // ---- A8 zero + x(s=0) ----
  for (int i = tid; i < 16*168/4; i += 512) reinterpret_cast<unsigned*>(A8)[i] = 0u;
  __syncthreads();
  if (tid < 256){
    const int b = tid >> 4, c = tid & 15;
    A8[b*168 + 128 + c] = f2fp8(x_std[(b0+b)*S_*16 + c]);
  }

  const float lng = ln_g[w*16 + l15];
  const float lnb = ln_b[w*16 + l15];
  const float bb  = (l15 < 14) ? btil[l15] : 0.f;

  float c_st[4][4];
  #pragma unroll
  for (int q=0;q<4;++q)
    #pragma unroll
    for (int r=0;r<4;++r) c_st[q][r] = 0.f;

  __syncthreads();

  const f32x4 zz = {0.f, 0.f, 0.f, 0.f};
  const int a_off = l15*168 + lq*8;   // + kc*32

  for (int s = 0; s < S_; ++s){
    // ======== deferred heads for step s-1 (wave 7) ========
    if (w == 7 && s > 0){
      f32x4 hd = zz;
      #pragma unroll
      for (int kc=0;kc<4;++kc){
        bf16x8 ha = ldg8(&HN[l15*136 + kc*32 + lq*8]);
        bf16x8 hb = ldg8(Wh + ((kc*64 + l)*8));
        hd = __builtin_amdgcn_mfma_f32_16x16x32_bf16(ha, hb, hd, 0,0,0);
      }
      #pragma unroll
      for (int r=0;r<4;++r){
        const int b = b0 + lq*4 + r;
        const float v = hd[r] + bb;
        if (l15 < 6)       out_cmd[(b*S_ + (s-1))*6 + l15] = v;
        else if (l15 < 14) out_coord[(b*S_ + (s-1))*8 + (l15-6)] = v;
      }
    }

    // ======== Phase G: gates = ctx*16 + A8·B (fp8 MFMA; B in regs + LDS), cell update ========
    long afr[5];
    #pragma unroll
    for (int kc=0;kc<5;++kc)
      afr[kc] = *reinterpret_cast<const long*>(&A8[a_off + kc*32]);

    #pragma unroll
    for (int dtl=0; dtl<4; ++dtl){
      const int dt = w*4 + dtl;
      // LDS B-frags for kc=3,4 (issue early; lane-linear -> conflict-free)
      long bl[4][2];
      #pragma unroll
      for (int gt=0; gt<4; ++gt){
        const int n = gt*32 + dt;
        #pragma unroll
        for (int kcl=0; kcl<2; ++kcl)
          bl[gt][kcl] = *reinterpret_cast<const long*>(&Bw[((n*2 + kcl)*64 + l)*8]);
      }
      f32x4 az[4];
      #pragma unroll
      for (int gt=0; gt<4; ++gt) az[gt] = ctxr[dtl][gt];
      #pragma unroll
      for (int kc=0;kc<3;++kc)
        #pragma unroll
        for (int gt=0; gt<4; ++gt)
          az[gt] = __builtin_amdgcn_mfma_f32_16x16x32_fp8_fp8(afr[kc], bp[dtl][gt][kc], az[gt], 0,0,0);
      #pragma unroll
      for (int kcl=0;kcl<2;++kcl)
        #pragma unroll
        for (int gt=0; gt<4; ++gt)
          az[gt] = __builtin_amdgcn_mfma_f32_16x16x32_fp8_fp8(afr[3+kcl], bl[gt][kcl], az[gt], 0,0,0);
      #pragma unroll
      for (int r=0;r<4;++r){
        const float iv = sigf  (az[0][r]*0.0625f);
        const float fv = sigf  (az[1][r]*0.0625f);
        const float gv = tanhft(az[2][r]*0.0625f);
        const float ov = sigf  (az[3][r]*0.0625f);
        const float cc = fv*c_st[dtl][r] + iv*gv;
        c_st[dtl][r] = cc;
        HF[(lq*4 + r)*520 + dt*16 + l15] = __float2bfloat16(ov*tanhft(cc));
      }
    }
    __syncthreads();  // B1

    // ======== Phase R: h = h_full · W_hr^T (bf16 L2 stream, 4-group pipelined) ========
    f32x4 aA = zz, aB = zz;
    {
      bf16x8 wva[4], wvb[4];
      #pragma unroll
      for (int kk=0;kk<4;++kk) wva[kk] = ldg8(Wr2 + ((w*16 +  0 + kk)*64 + l)*8);
      #pragma unroll
      for (int kk=0;kk<4;++kk) wvb[kk] = ldg8(Wr2 + ((w*16 +  4 + kk)*64 + l)*8);
      #pragma unroll
      for (int kk=0;kk<4;++kk){
        bf16x8 a2 = ldg8(&HF[l15*520 + (0+kk)*32 + lq*8]);
        if (kk&1) aB = __builtin_amdgcn_mfma_f32_16x16x32_bf16(a2, wva[kk], aB, 0,0,0);
        else      aA = __builtin_amdgcn_mfma_f32_16x16x32_bf16(a2, wva[kk], aA, 0,0,0);
      }
      #pragma unroll
      for (int kk=0;kk<4;++kk) wva[kk] = ldg8(Wr2 + ((w*16 +  8 + kk)*64 + l)*8);
      #pragma unroll
      for (int kk=0;kk<4;++kk){
        bf16x8 a2 = ldg8(&HF[l15*520 + (4+kk)*32 + lq*8]);
        if (kk&1) aB = __builtin_amdgcn_mfma_f32_16x16x32_bf16(a2, wvb[kk], aB, 0,0,0);
        else      aA = __builtin_amdgcn_mfma_f32_16x16x32_bf16(a2, wvb[kk], aA, 0,0,0);
      }
      #pragma unroll
      for (int kk=0;kk<4;++kk) wvb[kk] = ldg8(Wr2 + ((w*16 + 12 + kk)*64 + l)*8);
      #pragma unroll
      for (int kk=0;kk<4;++kk){
        bf16x8 a2 = ldg8(&HF[l15*520 + (8+kk)*32 + lq*8]);
        if (kk&1) aB = __builtin_amdgcn_mfma_f32_16x16x32_bf16(a2, wva[kk], aB, 0,0,0);
        else      aA = __builtin_amdgcn_mfma_f32_16x16x32_bf16(a2, wva[kk], aA, 0,0,0);
      }
      #pragma unroll
      for (int kk=0;kk<4;++kk){
        bf16x8 a2 = ldg8(&HF[l15*520 + (12+kk)*32 + lq*8]);
        if (kk&1) aB = __builtin_amdgcn_mfma_f32_16x16x32_bf16(a2, wvb[kk], aB, 0,0,0);
        else      aA = __builtin_amdgcn_mfma_f32_16x16x32_bf16(a2, wvb[kk], aA, 0,0,0);
      }
    }
    f32x4 acc2 = aA + aB;

    // LN partials (butterfly over lane bits 0..3)
    float sm[4], sq[4];
    #pragma unroll
    for (int r=0;r<4;++r){
      float v = acc2[r];
      sm[r] = v; sq[r] = v*v;
      #pragma unroll
      for (int m=1;m<16;m<<=1){
        sm[r] += __shfl_xor(sm[r], m);
        sq[r] += __shfl_xor(sq[r], m);
      }
    }
    if (l15 == 0){
      #pragma unroll
      for (int r=0;r<4;++r){
        s_red[(w*16 + lq*4 + r)*2 + 0] = sm[r];
        s_red[(w*16 + lq*4 + r)*2 + 1] = sq[r];
      }
    }
    // x prefetch for step s+1
    if (s+1 < S_ && tid < 256){
      const int b = tid >> 4, c = tid & 15;
      A8[b*168 + 128 + c] = f2fp8(x_std[((b0+b)*S_ + s+1)*16 + c]);
    }
    __syncthreads();  // B2

    // ======== Phase F: finalize mu / rstd ========
    if (tid < 16){
      float m = 0.f, v = 0.f;
      #pragma unroll
      for (int ww=0; ww<8; ++ww){
        m += s_red[(ww*16 + tid)*2 + 0];
        v += s_red[(ww*16 + tid)*2 + 1];
      }
      m *= (1.f/128.f);
      v = v*(1.f/128.f) - m*m;
      s_mu[tid] = m;
      s_rs[tid] = rsqrtf(v + 1e-5f);
    }
    __syncthreads();  // B3

    // ======== Phase E: raw h -> A8 (fp8, recurrent); hn -> HN (bf16, for heads) ========
    #pragma unroll
    for (int r=0;r<4;++r){
      const int b = lq*4 + r;
      const float h  = acc2[r];
      const float hn = (h - s_mu[b]) * s_rs[b] * lng + lnb;
      HN[b*136 + w*16 + l15] = __float2bfloat16(hn);
      A8[b*168 + w*16 + l15] = f2fp8(h);
    }
    __syncthreads();  // B4
  }

  // ======== epilogue: heads for s = S_-1 (wave 7) ========
  if (w == 7){
    f32x4 hd = zz;
    #pragma unroll
    for (int kc=0;kc<4;++kc){
      bf16x8 ha = ldg8(&HN[l15*136 + kc*32 + lq*8]);
      bf16x8 hb = ldg8(Wh + ((kc*64 + l)*8));
      hd = __builtin_amdgcn_mfma_f32_16x16x32_bf16(ha, hb, hd, 0,0,0);
    }
    #pragma unroll
    for (int r=0;r<4;++r){
      const int b = b0 + lq*4 + r;
      const float v = hd[r] + bb;
      if (l15 < 6)       out_cmd[(b*S_ + (S_-1))*6 + l15] = v;
      else if (l15 < 14) out_coord[(b*S_ + (S_-1))*8 + (l15-6)] = v;
    }
  }
}

extern "C" void kernel_launch(void* const* d_in, const int* in_sizes, int n_in,
                              void* d_out, int out_size, void* d_ws, size_t ws_size,
                              hipStream_t stream)
{
  const float* x_std       = (const float*)d_in[0];
  const float* context     = (const float*)d_in[1];
  const float* W_cmd       = (const float*)d_in[2];
  const float* b_cmd       = (const float*)d_in[3];
  const float* W_coord     = (const float*)d_in[4];
  const float* b_coord     = (const float*)d_in[5];
  const float* W_head      = (const float*)d_in[6];
  const float* b_head      = (const float*)d_in[7];
  const float* W_ih        = (const float*)d_in[8];
  const float* W_hh        = (const float*)d_in[9];
  const float* W_hr        = (const float*)d_in[10];
  const float* b_ih        = (const float*)d_in[11];
  const float* b_hh        = (const float*)d_in[12];
  const float* ln_g        = (const float*)d_in[13];
  const float* ln_b        = (const float*)d_in[14];
  const float* W_out_cmd   = (const float*)d_in[15];
  const float* b_out_cmd   = (const float*)d_in[16];
  const float* W_out_coord = (const float*)d_in[17];
  const float* b_out_coord = (const float*)d_in[18];

  float* out = (float*)d_out;
  char*  ws  = (char*)d_ws;

  unsigned char*  Bp   = (unsigned char*)(ws);              // 327680 B
  __hip_bfloat16* Wr2  = (__hip_bfloat16*)(ws + 327680);    // 131072 -> 458752
  __hip_bfloat16* Wh   = (__hip_bfloat16*)(ws + 458752);    // 4096   -> 462848
  float* btil          = (float*)(ws + 462848);             // 64     -> 462912
  float* b_fold        = (float*)(ws + 462912);             // 8192   -> 471104
  float* W_comb        = (float*)(ws + 471104);             // 131072 (dead after k_bp)
  float* ctxT          = (float*)(ws + 471104 + 131072);    // 2 MB -> 2699328 total (~2.6 MB)

  k_fold<<<dim3(G4), dim3(64), 0, stream>>>(W_ih, W_cmd, b_cmd, W_coord, b_coord,
                                            W_head, b_head, W_comb, b_fold);
  k_bp<<<dim3(1280), dim3(256), 0, stream>>>(W_hh, W_comb, Bp);
  k_wr2<<<dim3(256), dim3(256), 0, stream>>>(W_hr, Wr2);
  k_wout<<<dim3(9), dim3(256), 0, stream>>>(W_out_cmd, W_out_coord, b_out_cmd, b_out_coord,
                                            Wh, btil);
  k_ctxT<<<dim3(G4), dim3(256), 0, stream>>>(context, W_ih, b_ih, b_hh, b_fold, ctxT);
  k_scan<<<dim3(16), dim3(512), 0, stream>>>(x_std, ctxT, Bp, Wr2, Wh, btil, ln_g, ln_b,
                                             out, out + B_*S_*6);
}

// Round 7
// 1863.460 us; speedup vs baseline: 37.9852x; 1.4833x over previous
//
#include <hip/hip_runtime.h>
#include <hip/hip_bf16.h>
#include <stdint.h>

#define B_   256
#define S_   256
#define DM   512
#define G4   2048
#define LAT  128
#define PR   128
#define NB   4      // batches per block -> 64 blocks

typedef __bf16 bf16x8 __attribute__((ext_vector_type(8)));
typedef float  f32x4  __attribute__((ext_vector_type(4)));

__device__ __forceinline__ bf16x8 ldg8(const __hip_bfloat16* p){
  uint4 v = *reinterpret_cast<const uint4*>(p);
  return __builtin_bit_cast(bf16x8, v);
}
__device__ __forceinline__ float sigf(float x){ return 1.f/(1.f+__expf(-x)); }
__device__ __forceinline__ float tanhft(float x){ return 1.f - 2.f/(__expf(2.f*x)+1.f); }
__device__ __forceinline__ unsigned char f2fp8(float x){
  return (unsigned char)(__builtin_amdgcn_cvt_pk_fp8_f32(x, x, 0, false) & 0xff);
}

// ================= prep 1: W_comb[2048][16] = W_ih[:, :512] · Wcat, + folded x-bias ===========
__global__ void k_fold(const float* __restrict__ W_ih,
                       const float* __restrict__ W_cmd, const float* __restrict__ b_cmd,
                       const float* __restrict__ W_coord, const float* __restrict__ b_coord,
                       const float* __restrict__ W_head, const float* __restrict__ b_head,
                       float* __restrict__ W_comb, float* __restrict__ b_fold)
{
  const int g = blockIdx.x;      // 2048
  const int lane = threadIdx.x;  // 64
  float p[17];
  #pragma unroll
  for (int k=0;k<17;++k) p[k]=0.f;
  for (int d = lane; d < DM; d += 64){
    float w = W_ih[g*640 + d];
    #pragma unroll
    for (int c=0;c<6;++c)  p[c]    += w * W_cmd[d*6+c];
    #pragma unroll
    for (int c=0;c<8;++c)  p[6+c]  += w * W_coord[d*8+c];
    p[14] += w * W_head[d*2+0];
    p[15] += w * W_head[d*2+1];
    p[16] += w * (b_cmd[d] + b_coord[d] + b_head[d]);
  }
  #pragma unroll
  for (int k=0;k<17;++k){
    #pragma unroll
    for (int off=32; off>0; off>>=1) p[k] += __shfl_xor(p[k], off);
  }
  if (lane == 0){
    #pragma unroll
    for (int k=0;k<16;++k) W_comb[g*16+k] = p[k];
    b_fold[g] = p[16];
  }
}

// ================= prep 2: gate-B fp8, scaled x16, fragment-linear ==========================
__global__ void k_bp(const float* __restrict__ Whh, const float* __restrict__ W_comb,
                     unsigned char* __restrict__ Bp)
{
  const int flat = blockIdx.x*256 + threadIdx.x;   // 1280 blocks -> 327680
  const int j   = flat & 7;
  const int l   = (flat >> 3) & 63;
  const int idx = flat >> 9;                        // n*5 + kc
  const int n   = idx / 5;
  const int kc  = idx - n*5;
  const int g   = n*16 + (l & 15);
  const int k   = kc*32 + ((l >> 4) & 3)*8 + j;
  float v = (k < 128) ? Whh[g*PR + k] : ((k < 144) ? W_comb[g*16 + (k-128)] : 0.f);
  Bp[flat] = f2fp8(16.f * v);
}

// ================= prep 3: W_hr bf16 fragment-linear (8 tiles) ==============================
__global__ void k_wr2(const float* __restrict__ Whr, __hip_bfloat16* __restrict__ Wr2)
{
  const int flat = blockIdx.x*256 + threadIdx.x;   // 256 blocks: 8*16*64*8 = 65536
  const int j   = flat & 7;
  const int l   = (flat >> 3) & 63;
  const int kc  = (flat >> 9) & 15;
  const int tn  = flat >> 13;                       // 0..7
  const int row = tn*16 + (l & 15);                 // p < 128
  const int d   = kc*32 + ((l >> 4) & 3)*8 + j;
  Wr2[flat] = __float2bfloat16(Whr[row*DM + d]);
}

// ================= prep 4: folded head weights W~[t][p] (coord absorbs cmd), + bias =========
__global__ void k_wout(const float* __restrict__ Wocmd, const float* __restrict__ Wocoord,
                       const float* __restrict__ bocmd, const float* __restrict__ bocoord,
                       __hip_bfloat16* __restrict__ Wh, float* __restrict__ btil)
{
  if (blockIdx.x == 8){
    const int t = threadIdx.x;
    if (t < 16){
      float bv = 0.f;
      if (t < 6) bv = bocmd[t];
      else if (t < 14){
        bv = bocoord[t-6];
        for (int k=0;k<6;++k) bv += Wocoord[(t-6)*134 + 128 + k]*bocmd[k];
      }
      btil[t] = bv;
    }
    return;
  }
  const int flat = blockIdx.x*256 + threadIdx.x;   // 0..2047
  const int j  = flat & 7;
  const int l  = (flat >> 3) & 63;
  const int kc = flat >> 9;                         // 0..3
  const int t  = l & 15;
  const int p  = kc*32 + ((l >> 4) & 3)*8 + j;
  float v = 0.f;
  if (t < 6) v = Wocmd[t*PR + p];
  else if (t < 14){
    v = Wocoord[(t-6)*134 + p];
    for (int k=0;k<6;++k) v += Wocoord[(t-6)*134 + 128 + k]*Wocmd[k*PR + p];
  }
  Wh[flat] = __float2bfloat16(v);
}

// ================= prep 5: ctxB[b][g] = b_ih+b_hh+b_fold + ctx[b]·W_ih[g,512:] (b-major) ====
__global__ void k_ctx(const float* __restrict__ context, const float* __restrict__ W_ih,
                      const float* __restrict__ b_ih, const float* __restrict__ b_hh,
                      const float* __restrict__ b_fold, float* __restrict__ ctxB)
{
  const int idx = blockIdx.x*256 + threadIdx.x;   // 2048 blocks * 256 = B_*G4
  const int b = idx >> 11;
  const int g = idx & 2047;
  float a = b_ih[g] + b_hh[g] + b_fold[g];
  const float4* cp = reinterpret_cast<const float4*>(context + b*LAT);
  const float4* wp = reinterpret_cast<const float4*>(W_ih + g*640 + DM);
  #pragma unroll 8
  for (int q=0; q<LAT/4; ++q){
    float4 c = cp[q], w = wp[q];
    a += c.x*w.x + c.y*w.y + c.z*w.z + c.w*w.w;
  }
  ctxB[idx] = a;   // [b][g]
}

// ================= fused MFMA LSTM scan: 64 blocks x 4 batches, 8 waves ======================
__global__ __launch_bounds__(512, 2)
void k_scan(const float* __restrict__ x_std,
            const float* __restrict__ ctxB,
            const unsigned char* __restrict__ Bp,
            const __hip_bfloat16* __restrict__ Wr2,
            const __hip_bfloat16* __restrict__ Wh,
            const float* __restrict__ btil,
            const float* __restrict__ ln_g, const float* __restrict__ ln_b,
            float* __restrict__ out_cmd, float* __restrict__ out_coord)
{
  const int tid = threadIdx.x;
  const int w   = tid >> 6;        // wave 0..7
  const int l   = tid & 63;
  const int l15 = l & 15;
  const int lq  = l >> 4;          // 0..3
  const int b0  = blockIdx.x * NB; // 4 batches per block

  __shared__ __align__(8)  unsigned char  Bw[128*512];      // 64 KB: gate-B kc=4
  __shared__ __align__(16) float Graw[G4*NB];               // 32 KB raw gate sums [g][b]
  __shared__ __align__(16) __hip_bfloat16 HF[16*520];       // rows 0-3 valid, 4-15 zero
  __shared__ __align__(8)  unsigned char  A8[16*168];       // rows 0-3: h|x fp8; 4-15 zero
  __shared__ __align__(16) __hip_bfloat16 HN[16*136];       // rows 0-3 valid
  __shared__ __align__(16) float s_m[32], s_q[32];          // [w][4 batches]

  // ---- gate weights kc=0..3 -> registers (128 VGPR-equiv) ----
  long bp[4][4][4];
  {
    const long* Bpl = reinterpret_cast<const long*>(Bp);
    #pragma unroll
    for (int dtl=0; dtl<4; ++dtl)
      #pragma unroll
      for (int gt=0; gt<4; ++gt)
        #pragma unroll
        for (int kc=0; kc<4; ++kc){
          const int n = gt*32 + w*4 + dtl;
          bp[dtl][gt][kc] = Bpl[(n*5 + kc)*64 + l];
        }
  }
  // ---- gate weights kc=4 -> LDS ----
  {
    const long* Bpl = reinterpret_cast<const long*>(Bp);
    long* Bwl = reinterpret_cast<long*>(Bw);
    for (int i = tid; i < 128*64; i += 512)
      Bwl[i] = Bpl[((i>>6)*5 + 4)*64 + (i&63)];
  }
  // ---- ctx -> 16 regs/thread (step-invariant in act layout; thread owns d = tid) ----
  float cx[4][4];
  #pragma unroll
  for (int gt=0; gt<4; ++gt)
    #pragma unroll
    for (int b=0; b<NB; ++b)
      cx[gt][b] = ctxB[(b0+b)*G4 + gt*512 + tid];

  // ---- zero LDS state ----
  for (int i = tid; i < 16*520/2; i += 512) reinterpret_cast<unsigned*>(HF)[i] = 0u;
  for (int i = tid; i < 16*168/4; i += 512) reinterpret_cast<unsigned*>(A8)[i] = 0u;
  for (int i = tid; i < 16*136/2; i += 512) reinterpret_cast<unsigned*>(HN)[i] = 0u;
  __syncthreads();
  if (tid < 64){
    const int b = tid >> 4, c = tid & 15;
    A8[b*168 + 128 + c] = f2fp8(x_std[(b0+b)*S_*16 + c]);   // x at s=0
  }

  const float lng = ln_g[w*16 + l15];
  const float lnb = ln_b[w*16 + l15];
  const float bb  = (l15 < 14) ? btil[l15] : 0.f;

  float c_st[NB] = {0.f, 0.f, 0.f, 0.f};   // cell state: thread owns dim d = tid
  __syncthreads();

  const f32x4 zz = {0.f, 0.f, 0.f, 0.f};
  const int a_off = l15*168 + lq*8;

  for (int s = 0; s < S_; ++s){
    // ======== deferred heads for step s-1 (wave 7) ========
    if (w == 7 && s > 0){
      f32x4 hd = zz;
      #pragma unroll
      for (int kc=0;kc<4;++kc){
        bf16x8 ha = ldg8(&HN[l15*136 + kc*32 + lq*8]);
        bf16x8 hb = ldg8(Wh + (kc*64 + l)*8);
        hd = __builtin_amdgcn_mfma_f32_16x16x32_bf16(ha, hb, hd, 0,0,0);
      }
      if (lq == 0){
        #pragma unroll
        for (int r=0;r<NB;++r){
          const int b = b0 + r;
          const float v = hd[r] + bb;
          if (l15 < 6)       out_cmd[(b*S_ + (s-1))*6 + l15] = v;
          else if (l15 < 14) out_coord[(b*S_ + (s-1))*8 + (l15-6)] = v;
        }
      }
    }

    // ======== Phase G: raw gates = A8·B (fp8 MFMA) -> Graw ========
    long afr[5];
    #pragma unroll
    for (int kc=0;kc<5;++kc)
      afr[kc] = *reinterpret_cast<const long*>(&A8[a_off + kc*32]);

    #pragma unroll
    for (int dtl=0; dtl<4; ++dtl){
      const int dt = w*4 + dtl;
      long bl[4];
      #pragma unroll
      for (int gt=0; gt<4; ++gt)
        bl[gt] = *reinterpret_cast<const long*>(&Bw[((gt*32 + dt)*64 + l)*8]);
      f32x4 az[4] = {zz, zz, zz, zz};
      #pragma unroll
      for (int kc=0;kc<4;++kc)
        #pragma unroll
        for (int gt=0; gt<4; ++gt)
          az[gt] = __builtin_amdgcn_mfma_f32_16x16x32_fp8_fp8(afr[kc], bp[dtl][gt][kc], az[gt], 0,0,0);
      #pragma unroll
      for (int gt=0; gt<4; ++gt)
        az[gt] = __builtin_amdgcn_mfma_f32_16x16x32_fp8_fp8(afr[4], bl[gt], az[gt], 0,0,0);
      if (lq == 0){
        #pragma unroll
        for (int gt=0; gt<4; ++gt)
          *reinterpret_cast<f32x4*>(&Graw[(gt*512 + dt*16 + l15)*NB]) = az[gt];
      }
    }
    __syncthreads();  // BarA: Graw ready

    // ======== Phase A: activations, balanced (thread owns d = tid, 4 batches) ========
    {
      const int d = tid;
      f32x4 gv[4];
      #pragma unroll
      for (int gt=0; gt<4; ++gt)
        gv[gt] = *reinterpret_cast<const f32x4*>(&Graw[(gt*512 + d)*NB]);
      #pragma unroll
      for (int b=0; b<NB; ++b){
        const float iv = sigf  (gv[0][b]*0.0625f + cx[0][b]);
        const float fv = sigf  (gv[1][b]*0.0625f + cx[1][b]);
        const float gg = tanhft(gv[2][b]*0.0625f + cx[2][b]);
        const float ov = sigf  (gv[3][b]*0.0625f + cx[3][b]);
        const float cc = fv*c_st[b] + iv*gg;
        c_st[b] = cc;
        HF[b*520 + d] = __float2bfloat16(ov*tanhft(cc));
      }
    }
    __syncthreads();  // BarB: HF ready

    // ======== Phase R: h = h_full · W_hr^T (wave w owns p = w*16..w*16+15) ========
    f32x4 aA = zz, aB = zz;
    {
      bf16x8 wva[4], wvb[4];
      #pragma unroll
      for (int kk=0;kk<4;++kk) wva[kk] = ldg8(Wr2 + ((w*16 +  0 + kk)*64 + l)*8);
      #pragma unroll
      for (int kk=0;kk<4;++kk) wvb[kk] = ldg8(Wr2 + ((w*16 +  4 + kk)*64 + l)*8);
      #pragma unroll
      for (int kk=0;kk<4;++kk){
        bf16x8 a2 = ldg8(&HF[l15*520 + (0+kk)*32 + lq*8]);
        if (kk&1) aB = __builtin_amdgcn_mfma_f32_16x16x32_bf16(a2, wva[kk], aB, 0,0,0);
        else      aA = __builtin_amdgcn_mfma_f32_16x16x32_bf16(a2, wva[kk], aA, 0,0,0);
      }
      #pragma unroll
      for (int kk=0;kk<4;++kk) wva[kk] = ldg8(Wr2 + ((w*16 +  8 + kk)*64 + l)*8);
      #pragma unroll
      for (int kk=0;kk<4;++kk){
        bf16x8 a2 = ldg8(&HF[l15*520 + (4+kk)*32 + lq*8]);
        if (kk&1) aB = __builtin_amdgcn_mfma_f32_16x16x32_bf16(a2, wvb[kk], aB, 0,0,0);
        else      aA = __builtin_amdgcn_mfma_f32_16x16x32_bf16(a2, wvb[kk], aA, 0,0,0);
      }
      #pragma unroll
      for (int kk=0;kk<4;++kk) wvb[kk] = ldg8(Wr2 + ((w*16 + 12 + kk)*64 + l)*8);
      #pragma unroll
      for (int kk=0;kk<4;++kk){
        bf16x8 a2 = ldg8(&HF[l15*520 + (8+kk)*32 + lq*8]);
        if (kk&1) aB = __builtin_amdgcn_mfma_f32_16x16x32_bf16(a2, wva[kk], aB, 0,0,0);
        else      aA = __builtin_amdgcn_mfma_f32_16x16x32_bf16(a2, wva[kk], aA, 0,0,0);
      }
      #pragma unroll
      for (int kk=0;kk<4;++kk){
        bf16x8 a2 = ldg8(&HF[l15*520 + (12+kk)*32 + lq*8]);
        if (kk&1) aB = __builtin_amdgcn_mfma_f32_16x16x32_bf16(a2, wvb[kk], aB, 0,0,0);
        else      aA = __builtin_amdgcn_mfma_f32_16x16x32_bf16(a2, wvb[kk], aA, 0,0,0);
      }
    }
    f32x4 acc2 = aA + aB;    // rows 0-3 (lq==0) = batches, col = p = w*16+l15

    // LN partials: butterfly over l15 bits -> lane l==0 holds per-batch sums over this wave's 16 p
    float sm[4], sq[4];
    #pragma unroll
    for (int r=0;r<NB;++r){
      float v = acc2[r];
      sm[r] = v; sq[r] = v*v;
      #pragma unroll
      for (int m=1;m<16;m<<=1){
        sm[r] += __shfl_xor(sm[r], m);
        sq[r] += __shfl_xor(sq[r], m);
      }
    }
    if (l == 0){
      f32x4 vm = {sm[0], sm[1], sm[2], sm[3]};
      f32x4 vq = {sq[0], sq[1], sq[2], sq[3]};
      *reinterpret_cast<f32x4*>(&s_m[w*4]) = vm;
      *reinterpret_cast<f32x4*>(&s_q[w*4]) = vq;
    }
    __syncthreads();  // BarC: s_m/s_q ready

    // ======== Phase E: mu/rs (redundant per-thread), raw h -> A8, hn -> HN, x prefetch ========
    {
      f32x4 ms = zz, qs = zz;
      #pragma unroll
      for (int ww=0; ww<8; ++ww){
        ms += *reinterpret_cast<const f32x4*>(&s_m[ww*4]);
        qs += *reinterpret_cast<const f32x4*>(&s_q[ww*4]);
      }
      if (lq == 0){
        #pragma unroll
        for (int r=0;r<NB;++r){
          const float mu = ms[r] * (1.f/128.f);
          const float vr = qs[r] * (1.f/128.f) - mu*mu;
          const float rs = rsqrtf(vr + 1e-5f);
          const float h  = acc2[r];
          const float hn = (h - mu)*rs*lng + lnb;
          HN[r*136 + w*16 + l15] = __float2bfloat16(hn);
          A8[r*168 + w*16 + l15] = f2fp8(h);
        }
      }
    }
    if (s+1 < S_ && tid < 64){
      const int b = tid >> 4, c = tid & 15;
      A8[b*168 + 128 + c] = f2fp8(x_std[((b0+b)*S_ + s+1)*16 + c]);
    }
    __syncthreads();  // BarD: A8/HN ready for next step
  }

  // ======== epilogue: heads for s = S_-1 (wave 7) ========
  if (w == 7){
    f32x4 hd = zz;
    #pragma unroll
    for (int kc=0;kc<4;++kc){
      bf16x8 ha = ldg8(&HN[l15*136 + kc*32 + lq*8]);
      bf16x8 hb = ldg8(Wh + (kc*64 + l)*8);
      hd = __builtin_amdgcn_mfma_f32_16x16x32_bf16(ha, hb, hd, 0,0,0);
    }
    if (lq == 0){
      #pragma unroll
      for (int r=0;r<NB;++r){
        const int b = b0 + r;
        const float v = hd[r] + bb;
        if (l15 < 6)       out_cmd[(b*S_ + (S_-1))*6 + l15] = v;
        else if (l15 < 14) out_coord[(b*S_ + (S_-1))*8 + (l15-6)] = v;
      }
    }
  }
}

extern "C" void kernel_launch(void* const* d_in, const int* in_sizes, int n_in,
                              void* d_out, int out_size, void* d_ws, size_t ws_size,
                              hipStream_t stream)
{
  const float* x_std       = (const float*)d_in[0];
  const float* context     = (const float*)d_in[1];
  const float* W_cmd       = (const float*)d_in[2];
  const float* b_cmd       = (const float*)d_in[3];
  const float* W_coord     = (const float*)d_in[4];
  const float* b_coord     = (const float*)d_in[5];
  const float* W_head      = (const float*)d_in[6];
  const float* b_head      = (const float*)d_in[7];
  const float* W_ih        = (const float*)d_in[8];
  const float* W_hh        = (const float*)d_in[9];
  const float* W_hr        = (const float*)d_in[10];
  const float* b_ih        = (const float*)d_in[11];
  const float* b_hh        = (const float*)d_in[12];
  const float* ln_g        = (const float*)d_in[13];
  const float* ln_b        = (const float*)d_in[14];
  const float* W_out_cmd   = (const float*)d_in[15];
  const float* b_out_cmd   = (const float*)d_in[16];
  const float* W_out_coord = (const float*)d_in[17];
  const float* b_out_coord = (const float*)d_in[18];

  float* out = (float*)d_out;
  char*  ws  = (char*)d_ws;

  unsigned char*  Bp   = (unsigned char*)(ws);              // 327680 B
  __hip_bfloat16* Wr2  = (__hip_bfloat16*)(ws + 327680);    // 131072 -> 458752
  __hip_bfloat16* Wh   = (__hip_bfloat16*)(ws + 458752);    // 4096   -> 462848
  float* btil          = (float*)(ws + 462848);             // 64     -> 462912
  float* b_fold        = (float*)(ws + 462912);             // 8192   -> 471104
  float* W_comb        = (float*)(ws + 471104);             // 131072 (dead after k_bp)
  float* ctxB          = (float*)(ws + 471104 + 131072);    // 2 MB -> ~2.6 MB total

  k_fold<<<dim3(G4), dim3(64), 0, stream>>>(W_ih, W_cmd, b_cmd, W_coord, b_coord,
                                            W_head, b_head, W_comb, b_fold);
  k_bp<<<dim3(1280), dim3(256), 0, stream>>>(W_hh, W_comb, Bp);
  k_wr2<<<dim3(256), dim3(256), 0, stream>>>(W_hr, Wr2);
  k_wout<<<dim3(9), dim3(256), 0, stream>>>(W_out_cmd, W_out_coord, b_out_cmd, b_out_coord,
                                            Wh, btil);
  k_ctx<<<dim3((B_*G4)/256), dim3(256), 0, stream>>>(context, W_ih, b_ih, b_hh,
                                                     b_fold, ctxB);
  k_scan<<<dim3(B_/NB), dim3(512), 0, stream>>>(x_std, ctxB, Bp, Wr2, Wh, btil, ln_g, ln_b,
                                                out, out + B_*S_*6);
}